// Round 1
// baseline (773.534 us; speedup 1.0000x reference)
//
#include <hip/hip_runtime.h>
#include <math.h>
#include <stdint.h>

// UpsampleFlow3: fused exact 5-NN + softmax(-dist) + weighted flow sum.
// B=4, N=16384, M=4096, K=5, fp32.
//
// Round-4 structure: the brute kernel is VALU-issue-bound (99% VALUBusy,
// 27 ops x 16.8M pairs). This round replaces the all-pairs scan with an
// EXACT spatial grid:
//   - per-batch candidate bbox -> 32^3 Morton grid
//   - counting-sort candidates AND queries by cell (hist/scan/scatter)
//   - one wave = 64 Morton-adjacent queries; expanding Chebyshev ring walk
//     over candidate cells with conservative AABB lower bounds (scalar-pipe
//     skip), ring termination when ((r-1)*hmin)^2 > Tw (wave-max 5th-best)
//   - wide-span groups (Morton seams / sparse tail) -> sliced 8-wave brute
//     tail kernel, so the slowest wave stays bounded.
// Exactness: bounds carry an eps margin >> fp rounding; ring cap = full grid.

#define KNN 5
#define GRID 32
#define NCELL (GRID * GRID * GRID)
#define SPAN_TH 128
#define SLICES 8
#define BLOCK (SLICES * 64)
#define GRP_SHIFT 8

typedef unsigned int u32;

__device__ __forceinline__ float get_inv_sigma(const int* __restrict__ rf) {
    const int ri = rf[0];
    const float sigma = (ri >= 1 && ri <= 1000000) ? (float)ri : __int_as_float(ri);
    return 1.0f / sigma;
}

__device__ __forceinline__ float rfl_f(float v) {
    return __int_as_float(__builtin_amdgcn_readfirstlane(__float_as_int(v)));
}

__device__ __forceinline__ int cid1(float x, float lo, float ich) {
    const int c = (int)floorf((x - lo) * ich);
    return c < 0 ? 0 : (c > GRID - 1 ? GRID - 1 : c);
}

// 5-bit Morton spread: bit i -> bit 3i
__device__ __forceinline__ int spread5(int v) {
    int x = v & 31;
    x = (x | (x << 8)) & 0x0F00F;  // bits 0-3, 12
    x = (x | (x << 4)) & 0x010C3;  // bits 0,1,6,7,12
    x = (x | (x << 2)) & 0x01249;  // bits 0,3,6,9,12
    return x;
}

__constant__ int MLUT[32] = {
    0,    1,    8,    9,    64,   65,   72,   73,   512,  513,  520,
    521,  576,  577,  584,  585,  4096, 4097, 4104, 4105, 4160, 4161,
    4168, 4169, 4608, 4609, 4616, 4617, 4672, 4673, 4680, 4681};

// Compare-exchange: insert candidate (c,ci) into slot (k,ki); larger goes on.
#define CE_FULL(k, ki, c, ci)                          \
    {                                                  \
        const bool sw = (c) < (k);                     \
        const float vmn = fminf(k, c);                 \
        const float vmx = fmaxf(k, c);                 \
        const u32 nki = sw ? (ci) : (ki);              \
        const u32 nci = sw ? (ki) : (ci);              \
        (k) = vmn; (c) = vmx; (ki) = nki; (ci) = nci;  \
    }
#define CE_LAST(k, ki, c, ci)                          \
    {                                                  \
        const bool sw = (c) < (k);                     \
        (ki) = sw ? (ci) : (ki);                       \
        (k) = fminf(k, c);                             \
    }

// ---------------- legacy brute path (ws-too-small fallback) ----------------

__global__ __launch_bounds__(256)
void prep_kernel(const float* __restrict__ sxyz, const int* __restrict__ rf,
                 float4* __restrict__ pts, int M, int total) {
    const int t = blockIdx.x * 256 + threadIdx.x;
    if (t >= total) return;
    const float inv = get_inv_sigma(rf);
    const int b = t / M, m = t - b * M;
    const float* sb = sxyz + (size_t)b * 3 * M;
    const float x = sb[m] * inv;
    const float y = sb[M + m] * inv;
    const float z = sb[2 * M + m] * inv;
    pts[t] = make_float4(x, y, z, fmaf(x, x, fmaf(y, y, z * z)));
}

template <bool USE_PTS>
__global__ __launch_bounds__(BLOCK, 8)
void knn_kernel(const float* __restrict__ xyz,
                const float* __restrict__ sxyz,
                const float* __restrict__ sflow,
                const int* __restrict__ rf,
                const float4* __restrict__ pts,
                float* __restrict__ out,
                int N, int M) {
    __shared__ float sval_d[SLICES * KNN * 64];
    __shared__ u32   sval_i[SLICES * KNN * 64];

    const int tid  = threadIdx.x;
    const int lane = tid & 63;
    const int wid  = tid >> 6;
    const int swid = __builtin_amdgcn_readfirstlane(wid);
    const int b    = blockIdx.x >> GRP_SHIFT;
    const int grp  = blockIdx.x & ((1 << GRP_SHIFT) - 1);
    const int n    = grp * 64 + lane;

    const float inv = get_inv_sigma(rf);
    const float* qb = xyz + (size_t)b * 3 * N;
    const float qx = qb[n] * inv;
    const float qy = qb[N + n] * inv;
    const float qz = qb[2 * N + n] * inv;
    const float qq = fmaf(qx, qx, fmaf(qy, qy, qz * qz));

    const int CH = M / SLICES;
    const int j0 = swid * CH;

    float e0 = 1e30f, e1 = 1e30f, e2 = 1e30f, e3 = 1e30f, e4 = 1e30f;
    u32   i0 = 0, i1 = 0, i2 = 0, i3 = 0, i4 = 0;

    if constexpr (USE_PTS) {
        const float4* __restrict__ P = pts + (size_t)b * M + j0;
#pragma unroll 4
        for (int j = 0; j < CH; ++j) {
            const float4 p = P[j];
            float t = qx * p.x;
            t = fmaf(qy, p.y, t);
            t = fmaf(qz, p.z, t);
            float c = fmaf(-2.0f, t, p.w);
            u32 ci = (u32)(j0 + j);
            CE_FULL(e0, i0, c, ci)
            CE_FULL(e1, i1, c, ci)
            CE_FULL(e2, i2, c, ci)
            CE_FULL(e3, i3, c, ci)
            CE_LAST(e4, i4, c, ci)
        }
    } else {
        const float* __restrict__ sb = sxyz + (size_t)b * 3 * M;
#pragma unroll 4
        for (int j = 0; j < CH; ++j) {
            const float px = sb[j0 + j] * inv;
            const float py = sb[M + j0 + j] * inv;
            const float pz = sb[2 * M + j0 + j] * inv;
            const float pw = fmaf(px, px, fmaf(py, py, pz * pz));
            float t = qx * px;
            t = fmaf(qy, py, t);
            t = fmaf(qz, pz, t);
            float c = fmaf(-2.0f, t, pw);
            u32 ci = (u32)(j0 + j);
            CE_FULL(e0, i0, c, ci)
            CE_FULL(e1, i1, c, ci)
            CE_FULL(e2, i2, c, ci)
            CE_FULL(e3, i3, c, ci)
            CE_LAST(e4, i4, c, ci)
        }
    }

    sval_d[(wid * KNN + 0) * 64 + lane] = e0;  sval_i[(wid * KNN + 0) * 64 + lane] = i0;
    sval_d[(wid * KNN + 1) * 64 + lane] = e1;  sval_i[(wid * KNN + 1) * 64 + lane] = i1;
    sval_d[(wid * KNN + 2) * 64 + lane] = e2;  sval_i[(wid * KNN + 2) * 64 + lane] = i2;
    sval_d[(wid * KNN + 3) * 64 + lane] = e3;  sval_i[(wid * KNN + 3) * 64 + lane] = i3;
    sval_d[(wid * KNN + 4) * 64 + lane] = e4;  sval_i[(wid * KNN + 4) * 64 + lane] = i4;
    __syncthreads();

    if (wid == 0) {
        float m0 = 1e30f, m1 = 1e30f, m2 = 1e30f, m3 = 1e30f, m4 = 1e30f;
        u32   g0 = 0, g1 = 0, g2 = 0, g3 = 0, g4 = 0;
#pragma unroll
        for (int w = 0; w < SLICES; ++w) {
#pragma unroll
            for (int k = 0; k < KNN; ++k) {
                float c = sval_d[(w * KNN + k) * 64 + lane];
                u32  ci = sval_i[(w * KNN + k) * 64 + lane];
                CE_FULL(m0, g0, c, ci)
                CE_FULL(m1, g1, c, ci)
                CE_FULL(m2, g2, c, ci)
                CE_FULL(m3, g3, c, ci)
                CE_LAST(m4, g4, c, ci)
            }
        }

        const float d0 = sqrtf(fmaxf(m0 + qq, 1e-12f));
        const float d1 = sqrtf(fmaxf(m1 + qq, 1e-12f));
        const float d2 = sqrtf(fmaxf(m2 + qq, 1e-12f));
        const float d3 = sqrtf(fmaxf(m3 + qq, 1e-12f));
        const float d4 = sqrtf(fmaxf(m4 + qq, 1e-12f));
        const float w0 = 1.0f;
        const float w1 = expf(d0 - d1);
        const float w2 = expf(d0 - d2);
        const float w3 = expf(d0 - d3);
        const float w4 = expf(d0 - d4);
        const float inv_wsum = 1.0f / (w0 + w1 + w2 + w3 + w4);

        const float* fb = sflow + (size_t)b * 3 * M;
        float ax = 0.f, ay = 0.f, az = 0.f;
        ax = fmaf(w0, fb[g0], ax); ay = fmaf(w0, fb[M + g0], ay); az = fmaf(w0, fb[2 * M + g0], az);
        ax = fmaf(w1, fb[g1], ax); ay = fmaf(w1, fb[M + g1], ay); az = fmaf(w1, fb[2 * M + g1], az);
        ax = fmaf(w2, fb[g2], ax); ay = fmaf(w2, fb[M + g2], ay); az = fmaf(w2, fb[2 * M + g2], az);
        ax = fmaf(w3, fb[g3], ax); ay = fmaf(w3, fb[M + g3], ay); az = fmaf(w3, fb[2 * M + g3], az);
        ax = fmaf(w4, fb[g4], ax); ay = fmaf(w4, fb[M + g4], ay); az = fmaf(w4, fb[2 * M + g4], az);

        float* ob = out + (size_t)b * 3 * N;
        ob[n]         = ax * inv_wsum;
        ob[N + n]     = ay * inv_wsum;
        ob[2 * N + n] = az * inv_wsum;
    }
}

// ---------------- grid-path preprocessing ----------------

__global__ __launch_bounds__(256)
void bbox_kernel(const float* __restrict__ sxyz, const int* __restrict__ rf,
                 float* __restrict__ bbox, int M) {
    __shared__ float red[6][256];
    const int b = blockIdx.x, t = threadIdx.x;
    const float inv = get_inv_sigma(rf);
    const float* sb = sxyz + (size_t)b * 3 * M;
    float lx = 1e30f, ly = 1e30f, lz = 1e30f, hx = -1e30f, hy = -1e30f, hz = -1e30f;
    for (int m = t; m < M; m += 256) {
        const float x = sb[m] * inv, y = sb[M + m] * inv, z = sb[2 * M + m] * inv;
        lx = fminf(lx, x); hx = fmaxf(hx, x);
        ly = fminf(ly, y); hy = fmaxf(hy, y);
        lz = fminf(lz, z); hz = fmaxf(hz, z);
    }
    red[0][t] = lx; red[1][t] = ly; red[2][t] = lz;
    red[3][t] = hx; red[4][t] = hy; red[5][t] = hz;
    __syncthreads();
    for (int d = 128; d > 0; d >>= 1) {
        if (t < d) {
            red[0][t] = fminf(red[0][t], red[0][t + d]);
            red[1][t] = fminf(red[1][t], red[1][t + d]);
            red[2][t] = fminf(red[2][t], red[2][t + d]);
            red[3][t] = fmaxf(red[3][t], red[3][t + d]);
            red[4][t] = fmaxf(red[4][t], red[4][t + d]);
            red[5][t] = fmaxf(red[5][t], red[5][t + d]);
        }
        __syncthreads();
    }
    if (t == 0) {
        // cell size inflated so hi maps strictly below GRID -> cells contain points
        const float sc = (1.0f / GRID) * (1.0f + 4e-6f);
        bbox[b * 8 + 0] = red[0][0];
        bbox[b * 8 + 1] = red[1][0];
        bbox[b * 8 + 2] = red[2][0];
        bbox[b * 8 + 3] = (red[3][0] - red[0][0]) * sc + 1e-30f;
        bbox[b * 8 + 4] = (red[4][0] - red[1][0]) * sc + 1e-30f;
        bbox[b * 8 + 5] = (red[5][0] - red[2][0]) * sc + 1e-30f;
    }
}

__global__ __launch_bounds__(256)
void hist_kernel(const float* __restrict__ src, const int* __restrict__ rf,
                 const float* __restrict__ bbox, int* __restrict__ hist,
                 int len, int total) {
    const int t = blockIdx.x * 256 + threadIdx.x;
    if (t >= total) return;
    const int b = t / len, i = t - b * len;
    const float inv = get_inv_sigma(rf);
    const float* sb = src + (size_t)b * 3 * len;
    const float x = sb[i] * inv, y = sb[len + i] * inv, z = sb[2 * len + i] * inv;
    const float* bb = bbox + b * 8;
    const int cx = cid1(x, bb[0], 1.0f / bb[3]);
    const int cy = cid1(y, bb[1], 1.0f / bb[4]);
    const int cz = cid1(z, bb[2], 1.0f / bb[5]);
    const int cell = (spread5(cx) << 2) | (spread5(cy) << 1) | spread5(cz);
    atomicAdd(&hist[(size_t)b * NCELL + cell], 1);
}

__global__ __launch_bounds__(512)
void scan_kernel(const int* __restrict__ hist, int* __restrict__ off,
                 int* __restrict__ cur) {
    __shared__ int part[512];
    const int b = blockIdx.x, t = threadIdx.x;
    const int PER = NCELL / 512;  // 64
    const int hbase = b * NCELL + t * PER;
    int s = 0;
    for (int k = 0; k < PER; ++k) s += hist[hbase + k];
    part[t] = s;
    __syncthreads();
    for (int d = 1; d < 512; d <<= 1) {
        int x = (t >= d) ? part[t - d] : 0;
        __syncthreads();
        part[t] += x;
        __syncthreads();
    }
    int run = part[t] - s;  // exclusive prefix of this thread's chunk
    const int obase = b * (NCELL + 1) + t * PER;
    for (int k = 0; k < PER; ++k) {
        const int h = hist[hbase + k];
        off[obase + k] = run;
        cur[hbase + k] = run;
        run += h;
    }
    if (t == 511) off[b * (NCELL + 1) + NCELL] = run;
}

__global__ __launch_bounds__(256)
void scatter_kernel(const float* __restrict__ src, const int* __restrict__ rf,
                    const float* __restrict__ bbox, int* __restrict__ cur,
                    float4* __restrict__ dst, int* __restrict__ idxDst,
                    int len, int total, int isQuery) {
    const int t = blockIdx.x * 256 + threadIdx.x;
    if (t >= total) return;
    const int b = t / len, i = t - b * len;
    const float inv = get_inv_sigma(rf);
    const float* sb = src + (size_t)b * 3 * len;
    const float x = sb[i] * inv, y = sb[len + i] * inv, z = sb[2 * len + i] * inv;
    const float* bb = bbox + b * 8;
    const int cx = cid1(x, bb[0], 1.0f / bb[3]);
    const int cy = cid1(y, bb[1], 1.0f / bb[4]);
    const int cz = cid1(z, bb[2], 1.0f / bb[5]);
    const int cell = (spread5(cx) << 2) | (spread5(cy) << 1) | spread5(cz);
    const int slot = atomicAdd(&cur[(size_t)b * NCELL + cell], 1);
    if (isQuery) {
        dst[(size_t)b * len + slot] = make_float4(x, y, z, __int_as_float(i));
    } else {
        dst[(size_t)b * len + slot] =
            make_float4(x, y, z, fmaf(x, x, fmaf(y, y, z * z)));
        idxDst[(size_t)b * len + slot] = i;
    }
}

// ---------------- main grid kNN kernel ----------------

#define PROC(CX, CY, CZ)                                                          \
    {                                                                             \
        const int cell_ = (MLUT[CX] << 2) | (MLUT[CY] << 1) | MLUT[CZ];           \
        const int base_ = __builtin_amdgcn_readfirstlane(offb[cell_]);            \
        const int cnt_ = __builtin_amdgcn_readfirstlane(offb[cell_ + 1]) - base_; \
        if (cnt_ > 0) {                                                           \
            const float glx_ = fmaf((float)(CX), chx, lox);                       \
            const float gly_ = fmaf((float)(CY), chy, loy);                       \
            const float glz_ = fmaf((float)(CZ), chz, loz);                       \
            const float dx_ = fmaxf(fmaxf(glx_ - whx, wlx - (glx_ + chx)), 0.0f); \
            const float dy_ = fmaxf(fmaxf(gly_ - why, wly - (gly_ + chy)), 0.0f); \
            const float dz_ = fmaxf(fmaxf(glz_ - whz, wlz - (glz_ + chz)), 0.0f); \
            const float dl_ = fmaf(dx_, dx_, fmaf(dy_, dy_, dz_ * dz_));          \
            if (!(dl_ > Tw)) {                                                    \
                for (int j_ = 0; j_ < cnt_; ++j_) {                               \
                    const float4 p = Pb[base_ + j_];                              \
                    float t = qx * p.x;                                           \
                    t = fmaf(qy, p.y, t);                                         \
                    t = fmaf(qz, p.z, t);                                         \
                    float c = fmaf(-2.0f, t, p.w);                                \
                    u32 ci = (u32)(base_ + j_);                                   \
                    CE_FULL(e0, i0, c, ci)                                        \
                    CE_FULL(e1, i1, c, ci)                                        \
                    CE_FULL(e2, i2, c, ci)                                        \
                    CE_FULL(e3, i3, c, ci)                                        \
                    CE_LAST(e4, i4, c, ci)                                        \
                }                                                                 \
                float m4_ = e4 + qq;                                              \
                for (int mm_ = 1; mm_ < 64; mm_ <<= 1)                            \
                    m4_ = fmaxf(m4_, __shfl_xor(m4_, mm_, 64));                   \
                Tw = rfl_f(m4_);                                                  \
            }                                                                     \
        }                                                                         \
    }

__global__ __launch_bounds__(64)
void knn_grid_kernel(const float4* __restrict__ qS, const float4* __restrict__ ptsS,
                     const int* __restrict__ idxS, const int* __restrict__ offC,
                     const float* __restrict__ bbox, const float* __restrict__ sflow,
                     int* __restrict__ tailCnt, int* __restrict__ tailList,
                     float* __restrict__ out, int N, int M) {
    const int lane = threadIdx.x;
    const int gpb = N >> 6;
    const int b = blockIdx.x / gpb;
    const int grp = blockIdx.x - b * gpb;

    const float4 q4 = qS[(size_t)b * N + grp * 64 + lane];
    const float qx = q4.x, qy = q4.y, qz = q4.z;
    const int n = __float_as_int(q4.w);
    const float qq = fmaf(qx, qx, fmaf(qy, qy, qz * qz));

    // wave AABB of the 64 queries (then inflated by eps margin)
    float wlx = qx, wly = qy, wlz = qz, whx = qx, why = qy, whz = qz;
#pragma unroll
    for (int m = 1; m < 64; m <<= 1) {
        wlx = fminf(wlx, __shfl_xor(wlx, m, 64));
        whx = fmaxf(whx, __shfl_xor(whx, m, 64));
        wly = fminf(wly, __shfl_xor(wly, m, 64));
        why = fmaxf(why, __shfl_xor(why, m, 64));
        wlz = fminf(wlz, __shfl_xor(wlz, m, 64));
        whz = fmaxf(whz, __shfl_xor(whz, m, 64));
    }
    const float EPSM = 1e-3f;
    wlx = rfl_f(wlx) - EPSM; whx = rfl_f(whx) + EPSM;
    wly = rfl_f(wly) - EPSM; why = rfl_f(why) + EPSM;
    wlz = rfl_f(wlz) - EPSM; whz = rfl_f(whz) + EPSM;

    const float* bb = bbox + b * 8;
    const float lox = bb[0], loy = bb[1], loz = bb[2];
    const float chx = bb[3], chy = bb[4], chz = bb[5];
    const float hmin = fminf(chx, fminf(chy, chz));

    const int clx = cid1(wlx, lox, 1.0f / chx), cxh = cid1(whx, lox, 1.0f / chx);
    const int cly = cid1(wly, loy, 1.0f / chy), cyh = cid1(why, loy, 1.0f / chy);
    const int clz = cid1(wlz, loz, 1.0f / chz), czh = cid1(whz, loz, 1.0f / chz);

    // wide-span groups (Morton seams / sparse tail): defer to sliced brute
    const int span = (cxh - clx + 1) * (cyh - cly + 1) * (czh - clz + 1);
    if (span > SPAN_TH) {
        if (lane == 0) {
            const int idx = atomicAdd(tailCnt, 1);
            tailList[idx] = blockIdx.x;
        }
        return;
    }

    float e0 = 1e30f, e1 = 1e30f, e2 = 1e30f, e3 = 1e30f, e4 = 1e30f;
    u32 i0 = 0, i1 = 0, i2 = 0, i3 = 0, i4 = 0;
    float Tw = 1e30f;

    const float4* __restrict__ Pb = ptsS + (size_t)b * M;
    const int* __restrict__ offb = offC + (size_t)b * (NCELL + 1);

    for (int r = 0; r <= GRID; ++r) {
        if (r >= 2) {
            const float bd = (float)(r - 1) * hmin - EPSM;
            if (bd > 0.0f && bd * bd > Tw) break;
        }
        const int x0 = clx - r < 0 ? 0 : clx - r;
        const int x1 = cxh + r > GRID - 1 ? GRID - 1 : cxh + r;
        for (int cx = x0; cx <= x1; ++cx) {
            const int rx = cx < clx ? clx - cx : (cx > cxh ? cx - cxh : 0);
            const int y0 = cly - r < 0 ? 0 : cly - r;
            const int y1 = cyh + r > GRID - 1 ? GRID - 1 : cyh + r;
            for (int cy = y0; cy <= y1; ++cy) {
                const int ry = cy < cly ? cly - cy : (cy > cyh ? cy - cyh : 0);
                const int rxy = rx > ry ? rx : ry;
                if (rxy == r) {
                    const int z0 = clz - r < 0 ? 0 : clz - r;
                    const int z1 = czh + r > GRID - 1 ? GRID - 1 : czh + r;
                    for (int cz = z0; cz <= z1; ++cz) { PROC(cx, cy, cz) }
                } else {
                    int cz = clz - r;
                    if (cz >= 0) { PROC(cx, cy, cz) }
                    cz = czh + r;
                    if (cz <= GRID - 1) { PROC(cx, cy, cz) }
                }
            }
        }
    }

    // exact epilogue (same math as legacy)
    const float d0 = sqrtf(fmaxf(e0 + qq, 1e-12f));
    const float d1 = sqrtf(fmaxf(e1 + qq, 1e-12f));
    const float d2 = sqrtf(fmaxf(e2 + qq, 1e-12f));
    const float d3 = sqrtf(fmaxf(e3 + qq, 1e-12f));
    const float d4 = sqrtf(fmaxf(e4 + qq, 1e-12f));
    const float w0 = 1.0f;
    const float w1 = expf(d0 - d1);
    const float w2 = expf(d0 - d2);
    const float w3 = expf(d0 - d3);
    const float w4 = expf(d0 - d4);
    const float inv_wsum = 1.0f / (w0 + w1 + w2 + w3 + w4);

    const int* __restrict__ idxb = idxS + (size_t)b * M;
    const int g0 = idxb[i0], g1 = idxb[i1], g2 = idxb[i2], g3 = idxb[i3], g4 = idxb[i4];
    const float* fb = sflow + (size_t)b * 3 * M;
    float ax = 0.f, ay = 0.f, az = 0.f;
    ax = fmaf(w0, fb[g0], ax); ay = fmaf(w0, fb[M + g0], ay); az = fmaf(w0, fb[2 * M + g0], az);
    ax = fmaf(w1, fb[g1], ax); ay = fmaf(w1, fb[M + g1], ay); az = fmaf(w1, fb[2 * M + g1], az);
    ax = fmaf(w2, fb[g2], ax); ay = fmaf(w2, fb[M + g2], ay); az = fmaf(w2, fb[2 * M + g2], az);
    ax = fmaf(w3, fb[g3], ax); ay = fmaf(w3, fb[M + g3], ay); az = fmaf(w3, fb[2 * M + g3], az);
    ax = fmaf(w4, fb[g4], ax); ay = fmaf(w4, fb[M + g4], ay); az = fmaf(w4, fb[2 * M + g4], az);

    float* ob = out + (size_t)b * 3 * N;
    ob[n]         = ax * inv_wsum;
    ob[N + n]     = ay * inv_wsum;
    ob[2 * N + n] = az * inv_wsum;
}

// tail kernel: sliced 8-wave brute over sorted candidates for deferred groups
__global__ __launch_bounds__(BLOCK, 8)
void knn_tail_kernel(const float4* __restrict__ qS, const float4* __restrict__ ptsS,
                     const int* __restrict__ idxS, const int* __restrict__ tailCnt,
                     const int* __restrict__ tailList, const float* __restrict__ sflow,
                     float* __restrict__ out, int N, int M) {
    if ((int)blockIdx.x >= tailCnt[0]) return;
    const int g = tailList[blockIdx.x];
    const int gpb = N >> 6;
    const int b = g / gpb;
    const int grp = g - b * gpb;

    __shared__ float sval_d[SLICES * KNN * 64];
    __shared__ u32   sval_i[SLICES * KNN * 64];

    const int tid = threadIdx.x;
    const int lane = tid & 63;
    const int wid = tid >> 6;
    const int swid = __builtin_amdgcn_readfirstlane(wid);

    const float4 q4 = qS[(size_t)b * N + grp * 64 + lane];
    const float qx = q4.x, qy = q4.y, qz = q4.z;
    const int n = __float_as_int(q4.w);
    const float qq = fmaf(qx, qx, fmaf(qy, qy, qz * qz));

    const int CH = M / SLICES;
    const int j0 = swid * CH;

    float e0 = 1e30f, e1 = 1e30f, e2 = 1e30f, e3 = 1e30f, e4 = 1e30f;
    u32 i0 = 0, i1 = 0, i2 = 0, i3 = 0, i4 = 0;

    const float4* __restrict__ P = ptsS + (size_t)b * M + j0;
#pragma unroll 4
    for (int j = 0; j < CH; ++j) {
        const float4 p = P[j];
        float t = qx * p.x;
        t = fmaf(qy, p.y, t);
        t = fmaf(qz, p.z, t);
        float c = fmaf(-2.0f, t, p.w);
        u32 ci = (u32)(j0 + j);
        CE_FULL(e0, i0, c, ci)
        CE_FULL(e1, i1, c, ci)
        CE_FULL(e2, i2, c, ci)
        CE_FULL(e3, i3, c, ci)
        CE_LAST(e4, i4, c, ci)
    }

    sval_d[(wid * KNN + 0) * 64 + lane] = e0;  sval_i[(wid * KNN + 0) * 64 + lane] = i0;
    sval_d[(wid * KNN + 1) * 64 + lane] = e1;  sval_i[(wid * KNN + 1) * 64 + lane] = i1;
    sval_d[(wid * KNN + 2) * 64 + lane] = e2;  sval_i[(wid * KNN + 2) * 64 + lane] = i2;
    sval_d[(wid * KNN + 3) * 64 + lane] = e3;  sval_i[(wid * KNN + 3) * 64 + lane] = i3;
    sval_d[(wid * KNN + 4) * 64 + lane] = e4;  sval_i[(wid * KNN + 4) * 64 + lane] = i4;
    __syncthreads();

    if (wid == 0) {
        float m0 = 1e30f, m1 = 1e30f, m2 = 1e30f, m3 = 1e30f, m4 = 1e30f;
        u32 g0 = 0, g1 = 0, g2 = 0, g3 = 0, g4 = 0;
#pragma unroll
        for (int w = 0; w < SLICES; ++w) {
#pragma unroll
            for (int k = 0; k < KNN; ++k) {
                float c = sval_d[(w * KNN + k) * 64 + lane];
                u32 ci = sval_i[(w * KNN + k) * 64 + lane];
                CE_FULL(m0, g0, c, ci)
                CE_FULL(m1, g1, c, ci)
                CE_FULL(m2, g2, c, ci)
                CE_FULL(m3, g3, c, ci)
                CE_LAST(m4, g4, c, ci)
            }
        }

        const float d0 = sqrtf(fmaxf(m0 + qq, 1e-12f));
        const float d1 = sqrtf(fmaxf(m1 + qq, 1e-12f));
        const float d2 = sqrtf(fmaxf(m2 + qq, 1e-12f));
        const float d3 = sqrtf(fmaxf(m3 + qq, 1e-12f));
        const float d4 = sqrtf(fmaxf(m4 + qq, 1e-12f));
        const float w0 = 1.0f;
        const float w1 = expf(d0 - d1);
        const float w2 = expf(d0 - d2);
        const float w3 = expf(d0 - d3);
        const float w4 = expf(d0 - d4);
        const float inv_wsum = 1.0f / (w0 + w1 + w2 + w3 + w4);

        const int* __restrict__ idxb = idxS + (size_t)b * M;
        const int o0 = idxb[g0], o1 = idxb[g1], o2 = idxb[g2], o3 = idxb[g3], o4 = idxb[g4];
        const float* fb = sflow + (size_t)b * 3 * M;
        float ax = 0.f, ay = 0.f, az = 0.f;
        ax = fmaf(w0, fb[o0], ax); ay = fmaf(w0, fb[M + o0], ay); az = fmaf(w0, fb[2 * M + o0], az);
        ax = fmaf(w1, fb[o1], ax); ay = fmaf(w1, fb[M + o1], ay); az = fmaf(w1, fb[2 * M + o1], az);
        ax = fmaf(w2, fb[o2], ax); ay = fmaf(w2, fb[M + o2], ay); az = fmaf(w2, fb[2 * M + o2], az);
        ax = fmaf(w3, fb[o3], ax); ay = fmaf(w3, fb[M + o3], ay); az = fmaf(w3, fb[2 * M + o3], az);
        ax = fmaf(w4, fb[o4], ax); ay = fmaf(w4, fb[M + o4], ay); az = fmaf(w4, fb[2 * M + o4], az);

        float* ob = out + (size_t)b * 3 * N;
        ob[n]         = ax * inv_wsum;
        ob[N + n]     = ay * inv_wsum;
        ob[2 * N + n] = az * inv_wsum;
    }
}

extern "C" void kernel_launch(void* const* d_in, const int* in_sizes, int n_in,
                              void* d_out, int out_size, void* d_ws, size_t ws_size,
                              hipStream_t stream) {
    const float* xyz   = (const float*)d_in[0];
    const float* sxyz  = (const float*)d_in[1];
    const float* sflow = (const float*)d_in[2];
    const int*   rf    = (const int*)d_in[3];

    const int B = 4;
    const int N = in_sizes[0] / (3 * B);    // 16384
    const int M = in_sizes[1] / (3 * B);    // 4096
    float* out = (float*)d_out;
    const int gpb = N / 64;

    // workspace layout
    size_t o = 0;
    float4* ptsS = (float4*)((char*)d_ws + o); o += (size_t)B * M * sizeof(float4);
    float4* qS   = (float4*)((char*)d_ws + o); o += (size_t)B * N * sizeof(float4);
    int* idxS    = (int*)((char*)d_ws + o);    o += (size_t)B * M * 4;
    float* bbox  = (float*)((char*)d_ws + o);  o += 256;
    int* histC   = (int*)((char*)d_ws + o);    o += (size_t)B * NCELL * 4;
    int* histQ   = (int*)((char*)d_ws + o);    o += (size_t)B * NCELL * 4;
    int* tailCnt = (int*)((char*)d_ws + o);    o += 64;
    int* tailList= (int*)((char*)d_ws + o);    o += (size_t)B * gpb * 4;
    int* offC    = (int*)((char*)d_ws + o);    o += (size_t)B * (NCELL + 1) * 4;
    int* offQ    = (int*)((char*)d_ws + o);    o += (size_t)B * (NCELL + 1) * 4;
    int* curC    = (int*)((char*)d_ws + o);    o += (size_t)B * NCELL * 4;
    int* curQ    = (int*)((char*)d_ws + o);    o += (size_t)B * NCELL * 4;
    const size_t need = o;

    if (ws_size >= need && (N % 64) == 0 && (M % SLICES) == 0) {
        bbox_kernel<<<dim3(B), dim3(256), 0, stream>>>(sxyz, rf, bbox, M);
        // zero histC + histQ + tailCnt (contiguous)
        hipMemsetAsync(histC, 0, (size_t)B * NCELL * 8 + 64, stream);
        hist_kernel<<<dim3((B * M + 255) / 256), dim3(256), 0, stream>>>(
            sxyz, rf, bbox, histC, M, B * M);
        hist_kernel<<<dim3((B * N + 255) / 256), dim3(256), 0, stream>>>(
            xyz, rf, bbox, histQ, N, B * N);
        scan_kernel<<<dim3(B), dim3(512), 0, stream>>>(histC, offC, curC);
        scan_kernel<<<dim3(B), dim3(512), 0, stream>>>(histQ, offQ, curQ);
        scatter_kernel<<<dim3((B * M + 255) / 256), dim3(256), 0, stream>>>(
            sxyz, rf, bbox, curC, ptsS, idxS, M, B * M, 0);
        scatter_kernel<<<dim3((B * N + 255) / 256), dim3(256), 0, stream>>>(
            xyz, rf, bbox, curQ, qS, idxS, N, B * N, 1);
        knn_grid_kernel<<<dim3(B * gpb), dim3(64), 0, stream>>>(
            qS, ptsS, idxS, offC, bbox, sflow, tailCnt, tailList, out, N, M);
        knn_tail_kernel<<<dim3(B * gpb), dim3(BLOCK), 0, stream>>>(
            qS, ptsS, idxS, tailCnt, tailList, sflow, out, N, M);
    } else {
        const dim3 grid(B * (N / 64));
        const dim3 block(BLOCK);
        const size_t needOld = (size_t)B * M * sizeof(float4);
        if (ws_size >= needOld) {
            float4* pts = (float4*)d_ws;
            prep_kernel<<<dim3((B * M + 255) / 256), dim3(256), 0, stream>>>(
                sxyz, rf, pts, M, B * M);
            knn_kernel<true><<<grid, block, 0, stream>>>(xyz, sxyz, sflow, rf, pts, out, N, M);
        } else {
            knn_kernel<false><<<grid, block, 0, stream>>>(xyz, sxyz, sflow, rf, nullptr, out, N, M);
        }
    }
}

// Round 2
// 442.206 us; speedup vs baseline: 1.7493x; 1.7493x over previous
//
#include <hip/hip_runtime.h>
#include <math.h>
#include <stdint.h>

// UpsampleFlow3: fused exact 5-NN + softmax(-dist) + weighted flow sum.
// B=4, N=16384, M=4096, K=5, fp32.
//
// Round-5: round-4's grid prune cut VALU work 7x (29us busy) but ran at
// 1 wave/SIMD (occupancy 3%, VALUBusy 5%) -> 540us of naked load latency.
// This round keeps the prune, fixes the regime:
//  - 8 waves per 64-query group (512-thr block, brute-style), ring cells
//    round-robined by a deterministic counter; per-wave top-5 + LDS merge.
//    8192 waves = 8/SIMD (the brute ran 99% busy at this occupancy).
//  - GRID 32->16: 4096 cells for 4096 pts (was 87% empty cells).
//  - int2 {begin,end} per cell (one load), mindist test BEFORE any load,
//    candidate ladder unrolled x4 (4 s_load_dwordx4 in flight).
//  - shared LDS Tw (atomicMin, monotone, no barrier) tightens pruning.
//  - wide-span groups run the brute slice INLINE (no tail launch).
//  - prep fused: bbox, memset, hist(C+Q), scan(C+Q), scatter(C+Q) = 5+main.

#define KNN 5
#define GRID 16
#define NCELL (GRID * GRID * GRID)
#define SPAN_TH 128
#define SLICES 8
#define BLOCK (SLICES * 64)
#define EPSM 1e-3f

typedef unsigned int u32;

__device__ __forceinline__ float get_inv_sigma(const int* __restrict__ rf) {
    const int ri = rf[0];
    const float sigma = (ri >= 1 && ri <= 1000000) ? (float)ri : __int_as_float(ri);
    return 1.0f / sigma;
}

__device__ __forceinline__ float rfl_f(float v) {
    return __int_as_float(__builtin_amdgcn_readfirstlane(__float_as_int(v)));
}

__device__ __forceinline__ int cid1(float x, float lo, float ich) {
    const int c = (int)floorf((x - lo) * ich);
    return c < 0 ? 0 : (c > GRID - 1 ? GRID - 1 : c);
}

// 4-bit Morton spread: bit i -> bit 3i
__device__ __forceinline__ int sp4(int v) {
    int x = v & 15;
    x = (x | (x << 4)) & 0x0C3;
    x = (x | (x << 2)) & 0x249;
    return x;
}

// Compare-exchange: insert candidate (c,ci) into slot (k,ki); larger goes on.
#define CE_FULL(k, ki, c, ci)                          \
    {                                                  \
        const bool sw = (c) < (k);                     \
        const float vmn = fminf(k, c);                 \
        const float vmx = fmaxf(k, c);                 \
        const u32 nki = sw ? (ci) : (ki);              \
        const u32 nci = sw ? (ki) : (ci);              \
        (k) = vmn; (c) = vmx; (ki) = nki; (ci) = nci;  \
    }
#define CE_LAST(k, ki, c, ci)                          \
    {                                                  \
        const bool sw = (c) < (k);                     \
        (ki) = sw ? (ci) : (ki);                       \
        (k) = fminf(k, c);                             \
    }

#define LAD(P, CI)                                     \
    {                                                  \
        float t_ = qx * (P).x;                         \
        t_ = fmaf(qy, (P).y, t_);                      \
        t_ = fmaf(qz, (P).z, t_);                      \
        float c_ = fmaf(-2.0f, t_, (P).w);             \
        u32 ci_ = (u32)(CI);                           \
        CE_FULL(e0, i0, c_, ci_)                       \
        CE_FULL(e1, i1, c_, ci_)                       \
        CE_FULL(e2, i2, c_, ci_)                       \
        CE_FULL(e3, i3, c_, ci_)                       \
        CE_LAST(e4, i4, c_, ci_)                       \
    }

// ---------------- legacy brute path (ws-too-small fallback) ----------------

__global__ __launch_bounds__(256)
void prep_kernel(const float* __restrict__ sxyz, const int* __restrict__ rf,
                 float4* __restrict__ pts, int M, int total) {
    const int t = blockIdx.x * 256 + threadIdx.x;
    if (t >= total) return;
    const float inv = get_inv_sigma(rf);
    const int b = t / M, m = t - b * M;
    const float* sb = sxyz + (size_t)b * 3 * M;
    const float x = sb[m] * inv;
    const float y = sb[M + m] * inv;
    const float z = sb[2 * M + m] * inv;
    pts[t] = make_float4(x, y, z, fmaf(x, x, fmaf(y, y, z * z)));
}

template <bool USE_PTS>
__global__ __launch_bounds__(BLOCK, 8)
void knn_kernel(const float* __restrict__ xyz,
                const float* __restrict__ sxyz,
                const float* __restrict__ sflow,
                const int* __restrict__ rf,
                const float4* __restrict__ pts,
                float* __restrict__ out,
                int N, int M) {
    __shared__ float sval_d[SLICES * KNN * 64];
    __shared__ u32   sval_i[SLICES * KNN * 64];

    const int tid  = threadIdx.x;
    const int lane = tid & 63;
    const int wid  = tid >> 6;
    const int swid = __builtin_amdgcn_readfirstlane(wid);
    const int gpb  = N / 64;
    const int b    = blockIdx.x / gpb;
    const int grp  = blockIdx.x - b * gpb;
    const int n    = grp * 64 + lane;

    const float inv = get_inv_sigma(rf);
    const float* qb = xyz + (size_t)b * 3 * N;
    const float qx = qb[n] * inv;
    const float qy = qb[N + n] * inv;
    const float qz = qb[2 * N + n] * inv;
    const float qq = fmaf(qx, qx, fmaf(qy, qy, qz * qz));

    const int CH = M / SLICES;
    const int j0 = swid * CH;

    float e0 = 1e30f, e1 = 1e30f, e2 = 1e30f, e3 = 1e30f, e4 = 1e30f;
    u32   i0 = 0, i1 = 0, i2 = 0, i3 = 0, i4 = 0;

    if constexpr (USE_PTS) {
        const float4* __restrict__ P = pts + (size_t)b * M + j0;
#pragma unroll 4
        for (int j = 0; j < CH; ++j) {
            const float4 p = P[j];
            LAD(p, j0 + j)
        }
    } else {
        const float* __restrict__ sb = sxyz + (size_t)b * 3 * M;
#pragma unroll 4
        for (int j = 0; j < CH; ++j) {
            const float px = sb[j0 + j] * inv;
            const float py = sb[M + j0 + j] * inv;
            const float pz = sb[2 * M + j0 + j] * inv;
            const float pw = fmaf(px, px, fmaf(py, py, pz * pz));
            float4 p = make_float4(px, py, pz, pw);
            LAD(p, j0 + j)
        }
    }

    sval_d[(wid * KNN + 0) * 64 + lane] = e0;  sval_i[(wid * KNN + 0) * 64 + lane] = i0;
    sval_d[(wid * KNN + 1) * 64 + lane] = e1;  sval_i[(wid * KNN + 1) * 64 + lane] = i1;
    sval_d[(wid * KNN + 2) * 64 + lane] = e2;  sval_i[(wid * KNN + 2) * 64 + lane] = i2;
    sval_d[(wid * KNN + 3) * 64 + lane] = e3;  sval_i[(wid * KNN + 3) * 64 + lane] = i3;
    sval_d[(wid * KNN + 4) * 64 + lane] = e4;  sval_i[(wid * KNN + 4) * 64 + lane] = i4;
    __syncthreads();

    if (wid == 0) {
        float m0 = 1e30f, m1 = 1e30f, m2 = 1e30f, m3 = 1e30f, m4 = 1e30f;
        u32   g0 = 0, g1 = 0, g2 = 0, g3 = 0, g4 = 0;
#pragma unroll
        for (int w = 0; w < SLICES; ++w) {
#pragma unroll
            for (int k = 0; k < KNN; ++k) {
                float c = sval_d[(w * KNN + k) * 64 + lane];
                u32  ci = sval_i[(w * KNN + k) * 64 + lane];
                CE_FULL(m0, g0, c, ci)
                CE_FULL(m1, g1, c, ci)
                CE_FULL(m2, g2, c, ci)
                CE_FULL(m3, g3, c, ci)
                CE_LAST(m4, g4, c, ci)
            }
        }

        const float d0 = sqrtf(fmaxf(m0 + qq, 1e-12f));
        const float d1 = sqrtf(fmaxf(m1 + qq, 1e-12f));
        const float d2 = sqrtf(fmaxf(m2 + qq, 1e-12f));
        const float d3 = sqrtf(fmaxf(m3 + qq, 1e-12f));
        const float d4 = sqrtf(fmaxf(m4 + qq, 1e-12f));
        const float w0 = 1.0f;
        const float w1 = expf(d0 - d1);
        const float w2 = expf(d0 - d2);
        const float w3 = expf(d0 - d3);
        const float w4 = expf(d0 - d4);
        const float inv_wsum = 1.0f / (w0 + w1 + w2 + w3 + w4);

        const float* fb = sflow + (size_t)b * 3 * M;
        float ax = 0.f, ay = 0.f, az = 0.f;
        ax = fmaf(w0, fb[g0], ax); ay = fmaf(w0, fb[M + g0], ay); az = fmaf(w0, fb[2 * M + g0], az);
        ax = fmaf(w1, fb[g1], ax); ay = fmaf(w1, fb[M + g1], ay); az = fmaf(w1, fb[2 * M + g1], az);
        ax = fmaf(w2, fb[g2], ax); ay = fmaf(w2, fb[M + g2], ay); az = fmaf(w2, fb[2 * M + g2], az);
        ax = fmaf(w3, fb[g3], ax); ay = fmaf(w3, fb[M + g3], ay); az = fmaf(w3, fb[2 * M + g3], az);
        ax = fmaf(w4, fb[g4], ax); ay = fmaf(w4, fb[M + g4], ay); az = fmaf(w4, fb[2 * M + g4], az);

        float* ob = out + (size_t)b * 3 * N;
        ob[n]         = ax * inv_wsum;
        ob[N + n]     = ay * inv_wsum;
        ob[2 * N + n] = az * inv_wsum;
    }
}

// ---------------- grid-path preprocessing ----------------

__global__ __launch_bounds__(256)
void bbox_kernel(const float* __restrict__ sxyz, const int* __restrict__ rf,
                 float* __restrict__ bbox, int M) {
    __shared__ float red[6][256];
    const int b = blockIdx.x, t = threadIdx.x;
    const float inv = get_inv_sigma(rf);
    const float* sb = sxyz + (size_t)b * 3 * M;
    float lx = 1e30f, ly = 1e30f, lz = 1e30f, hx = -1e30f, hy = -1e30f, hz = -1e30f;
    for (int m = t; m < M; m += 256) {
        const float x = sb[m] * inv, y = sb[M + m] * inv, z = sb[2 * M + m] * inv;
        lx = fminf(lx, x); hx = fmaxf(hx, x);
        ly = fminf(ly, y); hy = fmaxf(hy, y);
        lz = fminf(lz, z); hz = fmaxf(hz, z);
    }
    red[0][t] = lx; red[1][t] = ly; red[2][t] = lz;
    red[3][t] = hx; red[4][t] = hy; red[5][t] = hz;
    __syncthreads();
    for (int d = 128; d > 0; d >>= 1) {
        if (t < d) {
            red[0][t] = fminf(red[0][t], red[0][t + d]);
            red[1][t] = fminf(red[1][t], red[1][t + d]);
            red[2][t] = fminf(red[2][t], red[2][t + d]);
            red[3][t] = fmaxf(red[3][t], red[3][t + d]);
            red[4][t] = fmaxf(red[4][t], red[4][t + d]);
            red[5][t] = fmaxf(red[5][t], red[5][t + d]);
        }
        __syncthreads();
    }
    if (t == 0) {
        const float sc = (1.0f / GRID) * (1.0f + 4e-6f);
        bbox[b * 8 + 0] = red[0][0];
        bbox[b * 8 + 1] = red[1][0];
        bbox[b * 8 + 2] = red[2][0];
        bbox[b * 8 + 3] = (red[3][0] - red[0][0]) * sc + 1e-30f;
        bbox[b * 8 + 4] = (red[4][0] - red[1][0]) * sc + 1e-30f;
        bbox[b * 8 + 5] = (red[5][0] - red[2][0]) * sc + 1e-30f;
    }
}

__device__ __forceinline__ int cell_of(const float* bb, float x, float y, float z) {
    const int cx = cid1(x, bb[0], 1.0f / bb[3]);
    const int cy = cid1(y, bb[1], 1.0f / bb[4]);
    const int cz = cid1(z, bb[2], 1.0f / bb[5]);
    return (sp4(cx) << 2) | (sp4(cy) << 1) | sp4(cz);
}

// fused C+Q histogram: slices 0..B-1 = candidates, B..2B-1 = queries
__global__ __launch_bounds__(256)
void hist_all_kernel(const float* __restrict__ xyz, const float* __restrict__ sxyz,
                     const int* __restrict__ rf, const float* __restrict__ bbox,
                     int* __restrict__ histAll, int N, int M, int B) {
    const int t = blockIdx.x * 256 + threadIdx.x;
    const int TC = B * M;
    const float inv = get_inv_sigma(rf);
    if (t < TC) {
        const int b = t / M, i = t - b * M;
        const float* sb = sxyz + (size_t)b * 3 * M;
        const float x = sb[i] * inv, y = sb[M + i] * inv, z = sb[2 * M + i] * inv;
        const int cell = cell_of(bbox + b * 8, x, y, z);
        atomicAdd(&histAll[(size_t)b * NCELL + cell], 1);
    } else if (t < TC + B * N) {
        const int t2 = t - TC;
        const int b = t2 / N, i = t2 - b * N;
        const float* qb = xyz + (size_t)b * 3 * N;
        const float x = qb[i] * inv, y = qb[N + i] * inv, z = qb[2 * N + i] * inv;
        const int cell = cell_of(bbox + b * 8, x, y, z);
        atomicAdd(&histAll[(size_t)(B + b) * NCELL + cell], 1);
    }
}

// one block per (which,b) slice; writes {begin,end} pairs + scatter cursor
__global__ __launch_bounds__(512)
void scan_kernel(const int* __restrict__ hist, int2* __restrict__ off2,
                 int* __restrict__ cur) {
    __shared__ int part[512];
    const int blk = blockIdx.x, t = threadIdx.x;
    const int PER = NCELL / 512;  // 8
    const int hbase = blk * NCELL + t * PER;
    int s = 0;
#pragma unroll
    for (int k = 0; k < PER; ++k) s += hist[hbase + k];
    part[t] = s;
    __syncthreads();
    for (int d = 1; d < 512; d <<= 1) {
        int x = (t >= d) ? part[t - d] : 0;
        __syncthreads();
        part[t] += x;
        __syncthreads();
    }
    int run = part[t] - s;
#pragma unroll
    for (int k = 0; k < PER; ++k) {
        const int h = hist[hbase + k];
        off2[hbase + k] = make_int2(run, run + h);
        cur[hbase + k] = run;
        run += h;
    }
}

__global__ __launch_bounds__(256)
void scatter_all_kernel(const float* __restrict__ xyz, const float* __restrict__ sxyz,
                        const int* __restrict__ rf, const float* __restrict__ bbox,
                        int* __restrict__ curAll, float4* __restrict__ ptsS,
                        float4* __restrict__ qS, int* __restrict__ idxS,
                        int N, int M, int B) {
    const int t = blockIdx.x * 256 + threadIdx.x;
    const int TC = B * M;
    const float inv = get_inv_sigma(rf);
    if (t < TC) {
        const int b = t / M, i = t - b * M;
        const float* sb = sxyz + (size_t)b * 3 * M;
        const float x = sb[i] * inv, y = sb[M + i] * inv, z = sb[2 * M + i] * inv;
        const int cell = cell_of(bbox + b * 8, x, y, z);
        const int slot = atomicAdd(&curAll[(size_t)b * NCELL + cell], 1);
        ptsS[(size_t)b * M + slot] = make_float4(x, y, z, fmaf(x, x, fmaf(y, y, z * z)));
        idxS[(size_t)b * M + slot] = i;
    } else if (t < TC + B * N) {
        const int t2 = t - TC;
        const int b = t2 / N, i = t2 - b * N;
        const float* qb = xyz + (size_t)b * 3 * N;
        const float x = qb[i] * inv, y = qb[N + i] * inv, z = qb[2 * N + i] * inv;
        const int cell = cell_of(bbox + b * 8, x, y, z);
        const int slot = atomicAdd(&curAll[(size_t)(B + b) * NCELL + cell], 1);
        qS[(size_t)b * N + slot] = make_float4(x, y, z, __int_as_float(i));
    }
}

// ---------------- main grid kNN kernel: 8 waves per 64-query group ----------------

// Process one cell if owned by this wave (round-robin on deterministic counter).
#define PROCZ(CZ)                                                                   \
    {                                                                               \
        if (((ownctr++) & 7) == wid) {                                              \
            const float glz_ = fmaf((float)(CZ), chz, loz);                         \
            const float dz_ = fmaxf(fmaxf(glz_ - whz, wlz - (glz_ + chz)), 0.0f);   \
            const float dl_ = fmaf(dz_, dz_, dxy);                                  \
            if (!(dl_ > TwR)) {                                                     \
                const int cell_ = mxy | sp4(CZ);                                    \
                const int2 oo_ = off2b[cell_];                                      \
                const int base_ = __builtin_amdgcn_readfirstlane(oo_.x);            \
                const int end_  = __builtin_amdgcn_readfirstlane(oo_.y);            \
                if (end_ > base_) {                                                 \
                    const float old4_ = e4;                                         \
                    int j_ = base_;                                                 \
                    for (; j_ + 4 <= end_; j_ += 4) {                               \
                        const float4 p0_ = Pb[j_];                                  \
                        const float4 p1_ = Pb[j_ + 1];                              \
                        const float4 p2_ = Pb[j_ + 2];                              \
                        const float4 p3_ = Pb[j_ + 3];                              \
                        LAD(p0_, j_) LAD(p1_, j_ + 1)                               \
                        LAD(p2_, j_ + 2) LAD(p3_, j_ + 3)                           \
                    }                                                               \
                    for (; j_ < end_; ++j_) {                                       \
                        const float4 pp_ = Pb[j_];                                  \
                        LAD(pp_, j_)                                                \
                    }                                                               \
                    if (__any(e4 < old4_)) {                                        \
                        float m4_ = e4 + qq;                                        \
                        for (int mm_ = 1; mm_ < 64; mm_ <<= 1)                      \
                            m4_ = fmaxf(m4_, __shfl_xor(m4_, mm_, 64));             \
                        m4_ = rfl_f(m4_);                                           \
                        TwOwn = fminf(TwOwn, m4_);                                  \
                        TwR = fminf(TwR, m4_);                                      \
                        if (lane == 0) atomicMin(&twS, __float_as_int(m4_));        \
                    }                                                               \
                }                                                                   \
            }                                                                       \
        }                                                                           \
    }

__global__ __launch_bounds__(BLOCK, 8)
void knn_grid8_kernel(const float4* __restrict__ qS, const float4* __restrict__ ptsS,
                      const int* __restrict__ idxS, const int2* __restrict__ off2All,
                      const float* __restrict__ bbox, const float* __restrict__ sflow,
                      float* __restrict__ out, int N, int M) {
    __shared__ float sval_d[SLICES * KNN * 64];   // 10 KB
    __shared__ u32   sval_i[SLICES * KNN * 64];   // 10 KB
    __shared__ int   twS;

    const int tid  = threadIdx.x;
    const int lane = tid & 63;
    const int wid  = tid >> 6;
    const int swid = __builtin_amdgcn_readfirstlane(wid);
    const int gpb  = N >> 6;
    const int b    = blockIdx.x / gpb;
    const int grp  = blockIdx.x - b * gpb;

    if (tid == 0) twS = 0x7F800000;  // +inf
    __syncthreads();

    const float4 q4 = qS[(size_t)b * N + grp * 64 + lane];
    const float qx = q4.x, qy = q4.y, qz = q4.z;
    const int n = __float_as_int(q4.w);
    const float qq = fmaf(qx, qx, fmaf(qy, qy, qz * qz));

    // wave AABB of the 64 queries (identical in all 8 waves), inflated by eps
    float wlx = qx, wly = qy, wlz = qz, whx = qx, why = qy, whz = qz;
#pragma unroll
    for (int m = 1; m < 64; m <<= 1) {
        wlx = fminf(wlx, __shfl_xor(wlx, m, 64));
        whx = fmaxf(whx, __shfl_xor(whx, m, 64));
        wly = fminf(wly, __shfl_xor(wly, m, 64));
        why = fmaxf(why, __shfl_xor(why, m, 64));
        wlz = fminf(wlz, __shfl_xor(wlz, m, 64));
        whz = fmaxf(whz, __shfl_xor(whz, m, 64));
    }
    wlx = rfl_f(wlx) - EPSM; whx = rfl_f(whx) + EPSM;
    wly = rfl_f(wly) - EPSM; why = rfl_f(why) + EPSM;
    wlz = rfl_f(wlz) - EPSM; whz = rfl_f(whz) + EPSM;

    const float* bb = bbox + b * 8;
    const float lox = bb[0], loy = bb[1], loz = bb[2];
    const float chx = bb[3], chy = bb[4], chz = bb[5];
    const float hmin = fminf(chx, fminf(chy, chz));

    const int clx = cid1(wlx, lox, 1.0f / chx), cxh = cid1(whx, lox, 1.0f / chx);
    const int cly = cid1(wly, loy, 1.0f / chy), cyh = cid1(why, loy, 1.0f / chy);
    const int clz = cid1(wlz, loz, 1.0f / chz), czh = cid1(whz, loz, 1.0f / chz);

    float e0 = 1e30f, e1 = 1e30f, e2 = 1e30f, e3 = 1e30f, e4 = 1e30f;
    u32 i0 = 0, i1 = 0, i2 = 0, i3 = 0, i4 = 0;

    const float4* __restrict__ Pb = ptsS + (size_t)b * M;
    const int2* __restrict__ off2b = off2All + (size_t)b * NCELL;

    const int span = (cxh - clx + 1) * (cyh - cly + 1) * (czh - clz + 1);
    if (span > SPAN_TH) {
        // inline sliced brute over sorted candidates (rare: Morton seams)
        const int CH = M / SLICES;
        const int j0 = swid * CH;
        const float4* __restrict__ P = Pb + j0;
#pragma unroll 4
        for (int j = 0; j < CH; ++j) {
            const float4 p = P[j];
            LAD(p, j0 + j)
        }
    } else {
        float TwOwn = 1e30f, TwR = 1e30f;
        int ownctr = 0;
        for (int r = 0; r <= GRID; ++r) {
            TwR = fminf(TwOwn, __int_as_float(__hip_atomic_load(
                                   &twS, __ATOMIC_RELAXED, __HIP_MEMORY_SCOPE_WORKGROUP)));
            if (r >= 2) {
                const float bd = (float)(r - 1) * hmin - EPSM;
                if (bd > 0.0f && bd * bd > TwR) break;
            }
            const int x0 = clx - r < 0 ? 0 : clx - r;
            const int x1 = cxh + r > GRID - 1 ? GRID - 1 : cxh + r;
            const int y0 = cly - r < 0 ? 0 : cly - r;
            const int y1 = cyh + r > GRID - 1 ? GRID - 1 : cyh + r;
            const int z0 = clz - r < 0 ? 0 : clz - r;
            const int z1 = czh + r > GRID - 1 ? GRID - 1 : czh + r;
            for (int cx = x0; cx <= x1; ++cx) {
                const int rx = cx < clx ? clx - cx : (cx > cxh ? cx - cxh : 0);
                const float glx = fmaf((float)cx, chx, lox);
                const float dx = fmaxf(fmaxf(glx - whx, wlx - (glx + chx)), 0.0f);
                const float dxx = dx * dx;
                const int mx = sp4(cx) << 2;
                for (int cy = y0; cy <= y1; ++cy) {
                    const int ry = cy < cly ? cly - cy : (cy > cyh ? cy - cyh : 0);
                    const float gly = fmaf((float)cy, chy, loy);
                    const float dy = fmaxf(fmaxf(gly - why, wly - (gly + chy)), 0.0f);
                    const float dxy = fmaf(dy, dy, dxx);
                    const int mxy = mx | (sp4(cy) << 1);
                    if ((rx > ry ? rx : ry) == r) {
                        for (int cz = z0; cz <= z1; ++cz) { PROCZ(cz) }
                    } else {
                        if (clz - r >= 0) { PROCZ(clz - r) }
                        if (czh + r <= GRID - 1) { PROCZ(czh + r) }
                    }
                }
            }
        }
    }

    sval_d[(wid * KNN + 0) * 64 + lane] = e0;  sval_i[(wid * KNN + 0) * 64 + lane] = i0;
    sval_d[(wid * KNN + 1) * 64 + lane] = e1;  sval_i[(wid * KNN + 1) * 64 + lane] = i1;
    sval_d[(wid * KNN + 2) * 64 + lane] = e2;  sval_i[(wid * KNN + 2) * 64 + lane] = i2;
    sval_d[(wid * KNN + 3) * 64 + lane] = e3;  sval_i[(wid * KNN + 3) * 64 + lane] = i3;
    sval_d[(wid * KNN + 4) * 64 + lane] = e4;  sval_i[(wid * KNN + 4) * 64 + lane] = i4;
    __syncthreads();

    if (wid == 0) {
        float m0 = 1e30f, m1 = 1e30f, m2 = 1e30f, m3 = 1e30f, m4 = 1e30f;
        u32 g0 = 0, g1 = 0, g2 = 0, g3 = 0, g4 = 0;
#pragma unroll
        for (int w = 0; w < SLICES; ++w) {
#pragma unroll
            for (int k = 0; k < KNN; ++k) {
                float c = sval_d[(w * KNN + k) * 64 + lane];
                u32 ci = sval_i[(w * KNN + k) * 64 + lane];
                CE_FULL(m0, g0, c, ci)
                CE_FULL(m1, g1, c, ci)
                CE_FULL(m2, g2, c, ci)
                CE_FULL(m3, g3, c, ci)
                CE_LAST(m4, g4, c, ci)
            }
        }

        const float d0 = sqrtf(fmaxf(m0 + qq, 1e-12f));
        const float d1 = sqrtf(fmaxf(m1 + qq, 1e-12f));
        const float d2 = sqrtf(fmaxf(m2 + qq, 1e-12f));
        const float d3 = sqrtf(fmaxf(m3 + qq, 1e-12f));
        const float d4 = sqrtf(fmaxf(m4 + qq, 1e-12f));
        const float w0 = 1.0f;
        const float w1 = expf(d0 - d1);
        const float w2 = expf(d0 - d2);
        const float w3 = expf(d0 - d3);
        const float w4 = expf(d0 - d4);
        const float inv_wsum = 1.0f / (w0 + w1 + w2 + w3 + w4);

        const int* __restrict__ idxb = idxS + (size_t)b * M;
        const int o0 = idxb[g0], o1 = idxb[g1], o2 = idxb[g2], o3 = idxb[g3], o4 = idxb[g4];
        const float* fb = sflow + (size_t)b * 3 * M;
        float ax = 0.f, ay = 0.f, az = 0.f;
        ax = fmaf(w0, fb[o0], ax); ay = fmaf(w0, fb[M + o0], ay); az = fmaf(w0, fb[2 * M + o0], az);
        ax = fmaf(w1, fb[o1], ax); ay = fmaf(w1, fb[M + o1], ay); az = fmaf(w1, fb[2 * M + o1], az);
        ax = fmaf(w2, fb[o2], ax); ay = fmaf(w2, fb[M + o2], ay); az = fmaf(w2, fb[2 * M + o2], az);
        ax = fmaf(w3, fb[o3], ax); ay = fmaf(w3, fb[M + o3], ay); az = fmaf(w3, fb[2 * M + o3], az);
        ax = fmaf(w4, fb[o4], ax); ay = fmaf(w4, fb[M + o4], ay); az = fmaf(w4, fb[2 * M + o4], az);

        float* ob = out + (size_t)b * 3 * N;
        ob[n]         = ax * inv_wsum;
        ob[N + n]     = ay * inv_wsum;
        ob[2 * N + n] = az * inv_wsum;
    }
}

extern "C" void kernel_launch(void* const* d_in, const int* in_sizes, int n_in,
                              void* d_out, int out_size, void* d_ws, size_t ws_size,
                              hipStream_t stream) {
    const float* xyz   = (const float*)d_in[0];
    const float* sxyz  = (const float*)d_in[1];
    const float* sflow = (const float*)d_in[2];
    const int*   rf    = (const int*)d_in[3];

    const int B = 4;
    const int N = in_sizes[0] / (3 * B);    // 16384
    const int M = in_sizes[1] / (3 * B);    // 4096
    float* out = (float*)d_out;

    // workspace layout
    size_t o = 0;
    float4* ptsS  = (float4*)((char*)d_ws + o); o += (size_t)B * M * sizeof(float4);
    float4* qS    = (float4*)((char*)d_ws + o); o += (size_t)B * N * sizeof(float4);
    int*   idxS   = (int*)((char*)d_ws + o);    o += (size_t)B * M * 4;
    float* bbox   = (float*)((char*)d_ws + o);  o += 256;
    int*   histAll= (int*)((char*)d_ws + o);    o += (size_t)2 * B * NCELL * 4;
    int*   curAll = (int*)((char*)d_ws + o);    o += (size_t)2 * B * NCELL * 4;
    int2*  off2All= (int2*)((char*)d_ws + o);   o += (size_t)2 * B * NCELL * 8;
    const size_t need = o;

    if (ws_size >= need && (N % 64) == 0 && (M % (8 * SLICES)) == 0) {
        const int totalHS = B * (M + N);
        bbox_kernel<<<dim3(B), dim3(256), 0, stream>>>(sxyz, rf, bbox, M);
        hipMemsetAsync(histAll, 0, (size_t)2 * B * NCELL * 4, stream);
        hist_all_kernel<<<dim3((totalHS + 255) / 256), dim3(256), 0, stream>>>(
            xyz, sxyz, rf, bbox, histAll, N, M, B);
        scan_kernel<<<dim3(2 * B), dim3(512), 0, stream>>>(histAll, off2All, curAll);
        scatter_all_kernel<<<dim3((totalHS + 255) / 256), dim3(256), 0, stream>>>(
            xyz, sxyz, rf, bbox, curAll, ptsS, qS, idxS, N, M, B);
        knn_grid8_kernel<<<dim3(B * (N / 64)), dim3(BLOCK), 0, stream>>>(
            qS, ptsS, idxS, off2All, bbox, sflow, out, N, M);
    } else {
        const dim3 grid(B * (N / 64));
        const dim3 block(BLOCK);
        const size_t needOld = (size_t)B * M * sizeof(float4);
        if (ws_size >= needOld) {
            float4* pts = (float4*)d_ws;
            prep_kernel<<<dim3((B * M + 255) / 256), dim3(256), 0, stream>>>(
                sxyz, rf, pts, M, B * M);
            knn_kernel<true><<<grid, block, 0, stream>>>(xyz, sxyz, sflow, rf, pts, out, N, M);
        } else {
            knn_kernel<false><<<grid, block, 0, stream>>>(xyz, sxyz, sflow, rf, nullptr, out, N, M);
        }
    }
}

// Round 4
// 312.941 us; speedup vs baseline: 2.4718x; 1.4131x over previous
//
#include <hip/hip_runtime.h>
#include <math.h>
#include <stdint.h>

// UpsampleFlow3: fused exact 5-NN + softmax(-dist) + weighted flow sum.
// B=4, N=16384, M=4096, K=5, fp32.
//
// Round-7 (post-mortems: r4 grid prune 1 wave/SIMD latency-bound; r5 8-wave
// fixed TLP but 8x-duplicated enumeration; r6 packed-key ladder FAILED
// correctness: 12-bit key quantization swaps near-tied 5th/6th neighbors
// whose flows are uncorrelated -> absmax 0.6):
//  - GRID=8 (512 cells, ~8 pts/cell), Morton-sorted candidates+queries.
//  - column (cx,cy) ownership round-robined across 8 waves; dxy rejects
//    whole columns; Tw (wave-max 5th-best) reduced once per improving column.
//  - EXACT (float,idx) CE ladder (r2-proven): selection exactness restored;
//    quantization only allowed in pruning bounds, never in compares.
//  - prep fused into ONE kernel (1 block/batch): bbox + LDS hist + LDS scan
//    + scatter. 2 launches total.

#define KNN 5
#define GRID 8
#define NCELL (GRID * GRID * GRID)
#define SPAN_TH 64
#define SLICES 8
#define BLOCK (SLICES * 64)
#define EPSM 1e-3f

typedef unsigned int u32;

__device__ __forceinline__ float get_inv_sigma(const int* __restrict__ rf) {
    const int ri = rf[0];
    const float sigma = (ri >= 1 && ri <= 1000000) ? (float)ri : __int_as_float(ri);
    return 1.0f / sigma;
}

__device__ __forceinline__ float rfl_f(float v) {
    return __int_as_float(__builtin_amdgcn_readfirstlane(__float_as_int(v)));
}

__device__ __forceinline__ int cid1(float x, float lo, float ich) {
    const int c = (int)floorf((x - lo) * ich);
    return c < 0 ? 0 : (c > GRID - 1 ? GRID - 1 : c);
}

// 3-bit Morton spread: bit i -> bit 3i
__device__ __forceinline__ int sp3(int v) {
    return (v & 1) | ((v & 2) << 2) | ((v & 4) << 4);
}

// Compare-exchange: insert candidate (c,ci) into slot (k,ki); larger goes on.
#define CE_FULL(k, ki, c, ci)                          \
    {                                                  \
        const bool sw = (c) < (k);                     \
        const float vmn = fminf(k, c);                 \
        const float vmx = fmaxf(k, c);                 \
        const u32 nki = sw ? (ci) : (ki);              \
        const u32 nci = sw ? (ki) : (ci);              \
        (k) = vmn; (c) = vmx; (ki) = nki; (ci) = nci;  \
    }
#define CE_LAST(k, ki, c, ci)                          \
    {                                                  \
        const bool sw = (c) < (k);                     \
        (ki) = sw ? (ci) : (ki);                       \
        (k) = fminf(k, c);                             \
    }

// exact ladder on d2' = |p|^2 - 2 q.p (qq deferred; order preserved)
#define LAD(P, CI)                                     \
    {                                                  \
        float t_ = qx * (P).x;                         \
        t_ = fmaf(qy, (P).y, t_);                      \
        t_ = fmaf(qz, (P).z, t_);                      \
        float c_ = fmaf(-2.0f, t_, (P).w);             \
        u32 ci_ = (u32)(CI);                           \
        CE_FULL(e0, i0, c_, ci_)                       \
        CE_FULL(e1, i1, c_, ci_)                       \
        CE_FULL(e2, i2, c_, ci_)                       \
        CE_FULL(e3, i3, c_, ci_)                       \
        CE_LAST(e4, i4, c_, ci_)                       \
    }

// ---------------- legacy brute path (ws-too-small fallback) ----------------

__global__ __launch_bounds__(256)
void prep_kernel(const float* __restrict__ sxyz, const int* __restrict__ rf,
                 float4* __restrict__ pts, int M, int total) {
    const int t = blockIdx.x * 256 + threadIdx.x;
    if (t >= total) return;
    const float inv = get_inv_sigma(rf);
    const int b = t / M, m = t - b * M;
    const float* sb = sxyz + (size_t)b * 3 * M;
    const float x = sb[m] * inv;
    const float y = sb[M + m] * inv;
    const float z = sb[2 * M + m] * inv;
    pts[t] = make_float4(x, y, z, fmaf(x, x, fmaf(y, y, z * z)));
}

template <bool USE_PTS>
__global__ __launch_bounds__(BLOCK, 8)
void knn_kernel(const float* __restrict__ xyz,
                const float* __restrict__ sxyz,
                const float* __restrict__ sflow,
                const int* __restrict__ rf,
                const float4* __restrict__ pts,
                float* __restrict__ out,
                int N, int M) {
    __shared__ float sval_d[SLICES * KNN * 64];
    __shared__ u32   sval_i[SLICES * KNN * 64];

    const int tid  = threadIdx.x;
    const int lane = tid & 63;
    const int wid  = tid >> 6;
    const int swid = __builtin_amdgcn_readfirstlane(wid);
    const int gpb  = N / 64;
    const int b    = blockIdx.x / gpb;
    const int grp  = blockIdx.x - b * gpb;
    const int n    = grp * 64 + lane;

    const float inv = get_inv_sigma(rf);
    const float* qb = xyz + (size_t)b * 3 * N;
    const float qx = qb[n] * inv;
    const float qy = qb[N + n] * inv;
    const float qz = qb[2 * N + n] * inv;
    const float qq = fmaf(qx, qx, fmaf(qy, qy, qz * qz));

    const int CH = M / SLICES;
    const int j0 = swid * CH;

    float e0 = 1e30f, e1 = 1e30f, e2 = 1e30f, e3 = 1e30f, e4 = 1e30f;
    u32   i0 = 0, i1 = 0, i2 = 0, i3 = 0, i4 = 0;

    if constexpr (USE_PTS) {
        const float4* __restrict__ P = pts + (size_t)b * M + j0;
#pragma unroll 4
        for (int j = 0; j < CH; ++j) {
            const float4 p = P[j];
            LAD(p, j0 + j)
        }
    } else {
        const float* __restrict__ sb = sxyz + (size_t)b * 3 * M;
#pragma unroll 4
        for (int j = 0; j < CH; ++j) {
            const float px = sb[j0 + j] * inv;
            const float py = sb[M + j0 + j] * inv;
            const float pz = sb[2 * M + j0 + j] * inv;
            const float pw = fmaf(px, px, fmaf(py, py, pz * pz));
            const float4 p = make_float4(px, py, pz, pw);
            LAD(p, j0 + j)
        }
    }

    sval_d[(wid * KNN + 0) * 64 + lane] = e0;  sval_i[(wid * KNN + 0) * 64 + lane] = i0;
    sval_d[(wid * KNN + 1) * 64 + lane] = e1;  sval_i[(wid * KNN + 1) * 64 + lane] = i1;
    sval_d[(wid * KNN + 2) * 64 + lane] = e2;  sval_i[(wid * KNN + 2) * 64 + lane] = i2;
    sval_d[(wid * KNN + 3) * 64 + lane] = e3;  sval_i[(wid * KNN + 3) * 64 + lane] = i3;
    sval_d[(wid * KNN + 4) * 64 + lane] = e4;  sval_i[(wid * KNN + 4) * 64 + lane] = i4;
    __syncthreads();

    if (wid == 0) {
        float m0 = 1e30f, m1 = 1e30f, m2 = 1e30f, m3 = 1e30f, m4 = 1e30f;
        u32   g0 = 0, g1 = 0, g2 = 0, g3 = 0, g4 = 0;
#pragma unroll
        for (int w = 0; w < SLICES; ++w) {
#pragma unroll
            for (int k = 0; k < KNN; ++k) {
                float c = sval_d[(w * KNN + k) * 64 + lane];
                u32  ci = sval_i[(w * KNN + k) * 64 + lane];
                CE_FULL(m0, g0, c, ci)
                CE_FULL(m1, g1, c, ci)
                CE_FULL(m2, g2, c, ci)
                CE_FULL(m3, g3, c, ci)
                CE_LAST(m4, g4, c, ci)
            }
        }

        const float d0 = sqrtf(fmaxf(m0 + qq, 1e-12f));
        const float d1 = sqrtf(fmaxf(m1 + qq, 1e-12f));
        const float d2 = sqrtf(fmaxf(m2 + qq, 1e-12f));
        const float d3 = sqrtf(fmaxf(m3 + qq, 1e-12f));
        const float d4 = sqrtf(fmaxf(m4 + qq, 1e-12f));
        const float w0 = 1.0f;
        const float w1 = expf(d0 - d1);
        const float w2 = expf(d0 - d2);
        const float w3 = expf(d0 - d3);
        const float w4 = expf(d0 - d4);
        const float inv_wsum = 1.0f / (w0 + w1 + w2 + w3 + w4);

        const float* fb = sflow + (size_t)b * 3 * M;
        float ax = 0.f, ay = 0.f, az = 0.f;
        ax = fmaf(w0, fb[g0], ax); ay = fmaf(w0, fb[M + g0], ay); az = fmaf(w0, fb[2 * M + g0], az);
        ax = fmaf(w1, fb[g1], ax); ay = fmaf(w1, fb[M + g1], ay); az = fmaf(w1, fb[2 * M + g1], az);
        ax = fmaf(w2, fb[g2], ax); ay = fmaf(w2, fb[M + g2], ay); az = fmaf(w2, fb[2 * M + g2], az);
        ax = fmaf(w3, fb[g3], ax); ay = fmaf(w3, fb[M + g3], ay); az = fmaf(w3, fb[2 * M + g3], az);
        ax = fmaf(w4, fb[g4], ax); ay = fmaf(w4, fb[M + g4], ay); az = fmaf(w4, fb[2 * M + g4], az);

        float* ob = out + (size_t)b * 3 * N;
        ob[n]         = ax * inv_wsum;
        ob[N + n]     = ay * inv_wsum;
        ob[2 * N + n] = az * inv_wsum;
    }
}

// ---------------- fused prep: bbox + hist + scan + scatter (1 block/batch) ----------------

__global__ __launch_bounds__(1024)
void prep_all_kernel(const float* __restrict__ xyz, const float* __restrict__ sxyz,
                     const int* __restrict__ rf, float* __restrict__ bbox,
                     int2* __restrict__ off2C, float4* __restrict__ ptsS,
                     float4* __restrict__ qS, int* __restrict__ idxS,
                     int N, int M) {
    __shared__ int hC[NCELL], hQ[NCELL];
    __shared__ int oC[NCELL], oQ[NCELL];
    __shared__ float sred[6][16];
    __shared__ float sbb[6];

    const int b = blockIdx.x, t = threadIdx.x;
    const int lane = t & 63, w = t >> 6;
    const float inv = get_inv_sigma(rf);
    const float* sb = sxyz + (size_t)b * 3 * M;
    const float* qb = xyz + (size_t)b * 3 * N;

    // 1. bbox over candidates
    float lx = 1e30f, ly = 1e30f, lz = 1e30f, hx = -1e30f, hy = -1e30f, hz = -1e30f;
    for (int m = t; m < M; m += 1024) {
        const float x = sb[m] * inv, y = sb[M + m] * inv, z = sb[2 * M + m] * inv;
        lx = fminf(lx, x); hx = fmaxf(hx, x);
        ly = fminf(ly, y); hy = fmaxf(hy, y);
        lz = fminf(lz, z); hz = fmaxf(hz, z);
    }
#pragma unroll
    for (int mm = 1; mm < 64; mm <<= 1) {
        lx = fminf(lx, __shfl_xor(lx, mm, 64));
        ly = fminf(ly, __shfl_xor(ly, mm, 64));
        lz = fminf(lz, __shfl_xor(lz, mm, 64));
        hx = fmaxf(hx, __shfl_xor(hx, mm, 64));
        hy = fmaxf(hy, __shfl_xor(hy, mm, 64));
        hz = fmaxf(hz, __shfl_xor(hz, mm, 64));
    }
    if (lane == 0) {
        sred[0][w] = lx; sred[1][w] = ly; sred[2][w] = lz;
        sred[3][w] = hx; sred[4][w] = hy; sred[5][w] = hz;
    }
    for (int c = t; c < NCELL; c += 1024) { hC[c] = 0; hQ[c] = 0; }
    __syncthreads();
    if (t == 0) {
        float Lx = sred[0][0], Ly = sred[1][0], Lz = sred[2][0];
        float Hx = sred[3][0], Hy = sred[4][0], Hz = sred[5][0];
        for (int k = 1; k < 16; ++k) {
            Lx = fminf(Lx, sred[0][k]); Ly = fminf(Ly, sred[1][k]); Lz = fminf(Lz, sred[2][k]);
            Hx = fmaxf(Hx, sred[3][k]); Hy = fmaxf(Hy, sred[4][k]); Hz = fmaxf(Hz, sred[5][k]);
        }
        const float sc = (1.0f / GRID) * (1.0f + 4e-6f);
        sbb[0] = Lx; sbb[1] = Ly; sbb[2] = Lz;
        sbb[3] = (Hx - Lx) * sc + 1e-30f;
        sbb[4] = (Hy - Ly) * sc + 1e-30f;
        sbb[5] = (Hz - Lz) * sc + 1e-30f;
        for (int k = 0; k < 6; ++k) bbox[b * 8 + k] = sbb[k];
    }
    __syncthreads();
    const float lox = sbb[0], loy = sbb[1], loz = sbb[2];
    const float icx = 1.0f / sbb[3], icy = 1.0f / sbb[4], icz = 1.0f / sbb[5];

#define CELL_OF(X, Y, Z) \
    ((sp3(cid1((X), lox, icx)) << 2) | (sp3(cid1((Y), loy, icy)) << 1) | sp3(cid1((Z), loz, icz)))

    // 2. hist
    for (int m = t; m < M; m += 1024) {
        const float x = sb[m] * inv, y = sb[M + m] * inv, z = sb[2 * M + m] * inv;
        atomicAdd(&hC[CELL_OF(x, y, z)], 1);
    }
    for (int i = t; i < N; i += 1024) {
        const float x = qb[i] * inv, y = qb[N + i] * inv, z = qb[2 * N + i] * inv;
        atomicAdd(&hQ[CELL_OF(x, y, z)], 1);
    }
    __syncthreads();

    // 3. scan (Hillis-Steele, inclusive) on NCELL cells
    if (t < NCELL) { oC[t] = hC[t]; oQ[t] = hQ[t]; }
    __syncthreads();
    for (int d = 1; d < NCELL; d <<= 1) {
        int vc = 0, vq = 0;
        if (t < NCELL && t >= d) { vc = oC[t - d]; vq = oQ[t - d]; }
        __syncthreads();
        if (t < NCELL && t >= d) { oC[t] += vc; oQ[t] += vq; }
        __syncthreads();
    }
    if (t < NCELL) {
        const int e = oC[t], h = hC[t];
        off2C[(size_t)b * NCELL + t] = make_int2(e - h, e);
        oC[t] = e - h;
        oQ[t] = oQ[t] - hQ[t];
    }
    __syncthreads();

    // 4. scatter
    for (int m = t; m < M; m += 1024) {
        const float x = sb[m] * inv, y = sb[M + m] * inv, z = sb[2 * M + m] * inv;
        const int slot = atomicAdd(&oC[CELL_OF(x, y, z)], 1);
        ptsS[(size_t)b * M + slot] = make_float4(x, y, z, fmaf(x, x, fmaf(y, y, z * z)));
        idxS[(size_t)b * M + slot] = m;
    }
    for (int i = t; i < N; i += 1024) {
        const float x = qb[i] * inv, y = qb[N + i] * inv, z = qb[2 * N + i] * inv;
        const int slot = atomicAdd(&oQ[CELL_OF(x, y, z)], 1);
        qS[(size_t)b * N + slot] = make_float4(x, y, z, __int_as_float(i));
    }
#undef CELL_OF
}

// ---------------- main grid kNN: 8 waves/group, column ownership ----------------

#define CELLP(CZ)                                                                   \
    {                                                                               \
        const float glz_ = fmaf((float)(CZ), chz, loz);                             \
        const float dz_ = fmaxf(fmaxf(glz_ - whz, wlz - (glz_ + chz)), 0.0f);       \
        const float dl_ = fmaf(dz_, dz_, dxy_);                                     \
        if (!(dl_ > TwR)) {                                                         \
            const int cell_ = mxy_ | sp3(CZ);                                       \
            const int2 oo_ = off2b[cell_];                                          \
            const int base_ = __builtin_amdgcn_readfirstlane(oo_.x);                \
            const int end_ = __builtin_amdgcn_readfirstlane(oo_.y);                 \
            int j_ = base_;                                                         \
            for (; j_ + 4 <= end_; j_ += 4) {                                       \
                const float4 p0_ = Pb[j_];                                          \
                const float4 p1_ = Pb[j_ + 1];                                      \
                const float4 p2_ = Pb[j_ + 2];                                      \
                const float4 p3_ = Pb[j_ + 3];                                      \
                LAD(p0_, j_) LAD(p1_, j_ + 1)                                       \
                LAD(p2_, j_ + 2) LAD(p3_, j_ + 3)                                   \
            }                                                                       \
            for (; j_ < end_; ++j_) {                                               \
                const float4 pp_ = Pb[j_];                                          \
                LAD(pp_, j_)                                                        \
            }                                                                       \
        }                                                                           \
    }

#define COLUMN(HAVEFULL)                                                            \
    {                                                                               \
        if (((colctr++) & 7) == wid) {                                              \
            TwR = fminf(TwOwn,                                                      \
                        __int_as_float(__hip_atomic_load(                           \
                            &twS, __ATOMIC_RELAXED, __HIP_MEMORY_SCOPE_WORKGROUP))); \
            const float gly_ = fmaf((float)cy, chy, loy);                           \
            const float dy_ = fmaxf(fmaxf(gly_ - why, wly - (gly_ + chy)), 0.0f);   \
            const float dxy_ = fmaf(dy_, dy_, dxx);                                 \
            if (!(dxy_ > TwR)) {                                                    \
                const int mxy_ = mx | (sp3(cy) << 1);                               \
                const float old4_ = e4;                                             \
                if (HAVEFULL) {                                                     \
                    for (int cz = z0; cz <= z1; ++cz) { CELLP(cz) }                 \
                } else {                                                            \
                    if (clz - r >= 0) { CELLP(clz - r) }                            \
                    if (czh + r <= GRID - 1) { CELLP(czh + r) }                     \
                }                                                                   \
                if (__any(e4 < old4_)) {                                            \
                    float m4_ = e4 + qq;                                            \
                    for (int mm_ = 1; mm_ < 64; mm_ <<= 1)                          \
                        m4_ = fmaxf(m4_, __shfl_xor(m4_, mm_, 64));                 \
                    m4_ = rfl_f(m4_);                                               \
                    TwOwn = fminf(TwOwn, m4_);                                      \
                    TwR = fminf(TwR, m4_);                                          \
                    if (lane == 0) atomicMin(&twS, __float_as_int(m4_));            \
                }                                                                   \
            }                                                                       \
        }                                                                           \
    }

__global__ __launch_bounds__(BLOCK, 8)
void knn_grid8_kernel(const float4* __restrict__ qS, const float4* __restrict__ ptsS,
                      const int* __restrict__ idxS, const int2* __restrict__ off2C,
                      const float* __restrict__ bbox, const float* __restrict__ sflow,
                      float* __restrict__ out, int N, int M) {
    __shared__ float sval_d[SLICES * KNN * 64];   // 10 KB
    __shared__ u32   sval_i[SLICES * KNN * 64];   // 10 KB
    __shared__ int   twS;

    const int tid  = threadIdx.x;
    const int lane = tid & 63;
    const int wid  = tid >> 6;
    const int swid = __builtin_amdgcn_readfirstlane(wid);
    const int gpb  = N >> 6;
    const int b    = blockIdx.x / gpb;
    const int grp  = blockIdx.x - b * gpb;

    if (tid == 0) twS = 0x7F800000;  // +inf
    __syncthreads();

    const float4 q4 = qS[(size_t)b * N + grp * 64 + lane];
    const float qx = q4.x, qy = q4.y, qz = q4.z;
    const int n = __float_as_int(q4.w);
    const float qq = fmaf(qx, qx, fmaf(qy, qy, qz * qz));

    // wave AABB (identical in all 8 waves), inflated by eps
    float wlx = qx, wly = qy, wlz = qz, whx = qx, why = qy, whz = qz;
#pragma unroll
    for (int m = 1; m < 64; m <<= 1) {
        wlx = fminf(wlx, __shfl_xor(wlx, m, 64));
        whx = fmaxf(whx, __shfl_xor(whx, m, 64));
        wly = fminf(wly, __shfl_xor(wly, m, 64));
        why = fmaxf(why, __shfl_xor(why, m, 64));
        wlz = fminf(wlz, __shfl_xor(wlz, m, 64));
        whz = fmaxf(whz, __shfl_xor(whz, m, 64));
    }
    wlx = rfl_f(wlx) - EPSM; whx = rfl_f(whx) + EPSM;
    wly = rfl_f(wly) - EPSM; why = rfl_f(why) + EPSM;
    wlz = rfl_f(wlz) - EPSM; whz = rfl_f(whz) + EPSM;

    const float* bb = bbox + b * 8;
    const float lox = bb[0], loy = bb[1], loz = bb[2];
    const float chx = bb[3], chy = bb[4], chz = bb[5];
    const float hmin = fminf(chx, fminf(chy, chz));

    const int clx = cid1(wlx, lox, 1.0f / chx), cxh = cid1(whx, lox, 1.0f / chx);
    const int cly = cid1(wly, loy, 1.0f / chy), cyh = cid1(why, loy, 1.0f / chy);
    const int clz = cid1(wlz, loz, 1.0f / chz), czh = cid1(whz, loz, 1.0f / chz);

    float e0 = 1e30f, e1 = 1e30f, e2 = 1e30f, e3 = 1e30f, e4 = 1e30f;
    u32   i0 = 0, i1 = 0, i2 = 0, i3 = 0, i4 = 0;

    const float4* __restrict__ Pb = ptsS + (size_t)b * M;
    const int2* __restrict__ off2b = off2C + (size_t)b * NCELL;

    const int span = (cxh - clx + 1) * (cyh - cly + 1) * (czh - clz + 1);
    if (span > SPAN_TH) {
        // inline sliced brute over sorted candidates (Morton seams, rare)
        const int CH = M / SLICES;
        const int j0 = swid * CH;
        const float4* __restrict__ P = Pb + j0;
#pragma unroll 4
        for (int j = 0; j < CH; ++j) {
            const float4 p = P[j];
            LAD(p, j0 + j)
        }
    } else {
        float TwOwn = 1e30f, TwR = 1e30f;
        int colctr = 0;
        for (int r = 0; r <= GRID; ++r) {
            TwR = fminf(TwOwn, __int_as_float(__hip_atomic_load(
                                   &twS, __ATOMIC_RELAXED, __HIP_MEMORY_SCOPE_WORKGROUP)));
            if (r >= 2) {
                const float bd = (float)(r - 1) * hmin - EPSM;
                if (bd > 0.0f && bd * bd > TwR) break;
            }
            const int x0 = clx - r < 0 ? 0 : clx - r;
            const int x1 = cxh + r > GRID - 1 ? GRID - 1 : cxh + r;
            const int y0 = cly - r < 0 ? 0 : cly - r;
            const int y1 = cyh + r > GRID - 1 ? GRID - 1 : cyh + r;
            const int z0 = clz - r < 0 ? 0 : clz - r;
            const int z1 = czh + r > GRID - 1 ? GRID - 1 : czh + r;
            for (int cx = x0; cx <= x1; ++cx) {
                const int rx = cx < clx ? clx - cx : (cx > cxh ? cx - cxh : 0);
                const float glx = fmaf((float)cx, chx, lox);
                const float dx = fmaxf(fmaxf(glx - whx, wlx - (glx + chx)), 0.0f);
                const float dxx = dx * dx;
                const int mx = sp3(cx) << 2;
                for (int cy = y0; cy <= y1; ++cy) {
                    const int ry = cy < cly ? cly - cy : (cy > cyh ? cy - cyh : 0);
                    if ((rx > ry ? rx : ry) == r) {
                        COLUMN(true)
                    } else {
                        COLUMN(false)
                    }
                }
            }
        }
    }

    sval_d[(wid * KNN + 0) * 64 + lane] = e0;  sval_i[(wid * KNN + 0) * 64 + lane] = i0;
    sval_d[(wid * KNN + 1) * 64 + lane] = e1;  sval_i[(wid * KNN + 1) * 64 + lane] = i1;
    sval_d[(wid * KNN + 2) * 64 + lane] = e2;  sval_i[(wid * KNN + 2) * 64 + lane] = i2;
    sval_d[(wid * KNN + 3) * 64 + lane] = e3;  sval_i[(wid * KNN + 3) * 64 + lane] = i3;
    sval_d[(wid * KNN + 4) * 64 + lane] = e4;  sval_i[(wid * KNN + 4) * 64 + lane] = i4;
    __syncthreads();

    if (wid == 0) {
        float m0 = 1e30f, m1 = 1e30f, m2 = 1e30f, m3 = 1e30f, m4 = 1e30f;
        u32 g0 = 0, g1 = 0, g2 = 0, g3 = 0, g4 = 0;
#pragma unroll
        for (int w = 0; w < SLICES; ++w) {
#pragma unroll
            for (int k = 0; k < KNN; ++k) {
                float c = sval_d[(w * KNN + k) * 64 + lane];
                u32 ci = sval_i[(w * KNN + k) * 64 + lane];
                CE_FULL(m0, g0, c, ci)
                CE_FULL(m1, g1, c, ci)
                CE_FULL(m2, g2, c, ci)
                CE_FULL(m3, g3, c, ci)
                CE_LAST(m4, g4, c, ci)
            }
        }

        const float d0 = sqrtf(fmaxf(m0 + qq, 1e-12f));
        const float d1 = sqrtf(fmaxf(m1 + qq, 1e-12f));
        const float d2 = sqrtf(fmaxf(m2 + qq, 1e-12f));
        const float d3 = sqrtf(fmaxf(m3 + qq, 1e-12f));
        const float d4 = sqrtf(fmaxf(m4 + qq, 1e-12f));
        const float w0 = 1.0f;
        const float w1 = expf(d0 - d1);
        const float w2 = expf(d0 - d2);
        const float w3 = expf(d0 - d3);
        const float w4 = expf(d0 - d4);
        const float inv_wsum = 1.0f / (w0 + w1 + w2 + w3 + w4);

        const int* __restrict__ idxb = idxS + (size_t)b * M;
        const int o0 = idxb[g0], o1 = idxb[g1], o2 = idxb[g2], o3 = idxb[g3], o4 = idxb[g4];
        const float* fb = sflow + (size_t)b * 3 * M;
        float ax = 0.f, ay = 0.f, az = 0.f;
        ax = fmaf(w0, fb[o0], ax); ay = fmaf(w0, fb[M + o0], ay); az = fmaf(w0, fb[2 * M + o0], az);
        ax = fmaf(w1, fb[o1], ax); ay = fmaf(w1, fb[M + o1], ay); az = fmaf(w1, fb[2 * M + o1], az);
        ax = fmaf(w2, fb[o2], ax); ay = fmaf(w2, fb[M + o2], ay); az = fmaf(w2, fb[2 * M + o2], az);
        ax = fmaf(w3, fb[o3], ax); ay = fmaf(w3, fb[M + o3], ay); az = fmaf(w3, fb[2 * M + o3], az);
        ax = fmaf(w4, fb[o4], ax); ay = fmaf(w4, fb[M + o4], ay); az = fmaf(w4, fb[2 * M + o4], az);

        float* ob = out + (size_t)b * 3 * N;
        ob[n]         = ax * inv_wsum;
        ob[N + n]     = ay * inv_wsum;
        ob[2 * N + n] = az * inv_wsum;
    }
}

extern "C" void kernel_launch(void* const* d_in, const int* in_sizes, int n_in,
                              void* d_out, int out_size, void* d_ws, size_t ws_size,
                              hipStream_t stream) {
    const float* xyz   = (const float*)d_in[0];
    const float* sxyz  = (const float*)d_in[1];
    const float* sflow = (const float*)d_in[2];
    const int*   rf    = (const int*)d_in[3];

    const int B = 4;
    const int N = in_sizes[0] / (3 * B);    // 16384
    const int M = in_sizes[1] / (3 * B);    // 4096
    float* out = (float*)d_out;

    // workspace layout
    size_t o = 0;
    float4* ptsS  = (float4*)((char*)d_ws + o); o += (size_t)B * M * sizeof(float4);
    float4* qS    = (float4*)((char*)d_ws + o); o += (size_t)B * N * sizeof(float4);
    int*   idxS   = (int*)((char*)d_ws + o);    o += (size_t)B * M * 4;
    float* bbox   = (float*)((char*)d_ws + o);  o += 256;
    int2*  off2C  = (int2*)((char*)d_ws + o);   o += (size_t)B * NCELL * 8;
    const size_t need = o;

    if (ws_size >= need && (N % 64) == 0 && (M % (8 * SLICES)) == 0) {
        prep_all_kernel<<<dim3(B), dim3(1024), 0, stream>>>(
            xyz, sxyz, rf, bbox, off2C, ptsS, qS, idxS, N, M);
        knn_grid8_kernel<<<dim3(B * (N / 64)), dim3(BLOCK), 0, stream>>>(
            qS, ptsS, idxS, off2C, bbox, sflow, out, N, M);
    } else {
        const dim3 grid(B * (N / 64));
        const dim3 block(BLOCK);
        const size_t needOld = (size_t)B * M * sizeof(float4);
        if (ws_size >= needOld) {
            float4* pts = (float4*)d_ws;
            prep_kernel<<<dim3((B * M + 255) / 256), dim3(256), 0, stream>>>(
                sxyz, rf, pts, M, B * M);
            knn_kernel<true><<<grid, block, 0, stream>>>(xyz, sxyz, sflow, rf, pts, out, N, M);
        } else {
            knn_kernel<false><<<grid, block, 0, stream>>>(xyz, sxyz, sflow, rf, nullptr, out, N, M);
        }
    }
}

// Round 6
// 269.549 us; speedup vs baseline: 2.8697x; 1.1610x over previous
//
#include <hip/hip_runtime.h>
#include <math.h>
#include <stdint.h>

// UpsampleFlow3: fused exact 5-NN + softmax(-dist) + weighted flow sum.
// B=4, N=16384, M=4096, K=5, fp32.
//
// Round-9 (post-mortems: r7 = 236us knn + 40us prep, eager scan + AABB-level
// prune too coarse; r8 FAILED determinism tripwire: cross-wave twS atomic
// bound was (a) computed wrong (qq added after the lane-reduce) and (b) read
// racily -> run-to-run divergence):
//  - phase 1: cooperative span-box scan + ONE barrier + cross-wave bound
//    merge in LDS (per-lane min over waves of e4, +qq, max over lanes) ->
//    deterministic tight group bound before any ring work.
//  - phase 2: expanding rings; termination bound = min(phase-1 merged bound,
//    own-wave max(e4+qq)) -- NO shared atomics, NO barriers in the loop;
//    control flow is a deterministic function of inputs.
//  - per-lane exact cell prune: skip cell iff __all(mindist(cell,q)^2 >
//    (e4+qq)*1.00001+eps) (clamp-based, 2 ops/dim).
//  - prep: 4 wide kernels (encoded-u32 atomic bbox, atomic hist, LDS scan,
//    atomic scatter).

#define KNN 5
#define GRID 8
#define NCELL (GRID * GRID * GRID)
#define SPAN_TH 64
#define SLICES 8
#define BLOCK (SLICES * 64)
#define EPSM 1e-3f

typedef unsigned int u32;

__device__ __forceinline__ float get_inv_sigma(const int* __restrict__ rf) {
    const int ri = rf[0];
    const float sigma = (ri >= 1 && ri <= 1000000) ? (float)ri : __int_as_float(ri);
    return 1.0f / sigma;
}

__device__ __forceinline__ float rfl_f(float v) {
    return __int_as_float(__builtin_amdgcn_readfirstlane(__float_as_int(v)));
}

__device__ __forceinline__ int cid1(float x, float lo, float ich) {
    const int c = (int)floorf((x - lo) * ich);
    return c < 0 ? 0 : (c > GRID - 1 ? GRID - 1 : c);
}

// 3-bit Morton spread: bit i -> bit 3i
__device__ __forceinline__ int sp3(int v) {
    return (v & 1) | ((v & 2) << 2) | ((v & 4) << 4);
}

// monotone float <-> u32 (for atomic min/max bbox)
__device__ __forceinline__ u32 fenc(float f) {
    const u32 b = __float_as_uint(f);
    return (b & 0x80000000u) ? ~b : (b | 0x80000000u);
}
__device__ __forceinline__ float fdec(u32 u) {
    return __uint_as_float((u & 0x80000000u) ? (u & 0x7FFFFFFFu) : ~u);
}

// shared grid geometry (identical formula at every use site -> identical fp)
__device__ __forceinline__ void bb_load(const u32* __restrict__ minU,
                                        const u32* __restrict__ maxU, int b,
                                        float& lox, float& loy, float& loz,
                                        float& chx, float& chy, float& chz) {
    const float sc = (1.0f / GRID) * (1.0f + 4e-6f);
    const float Lx = fdec(minU[b * 3 + 0]);
    const float Ly = fdec(minU[b * 3 + 1]);
    const float Lz = fdec(minU[b * 3 + 2]);
    lox = Lx; loy = Ly; loz = Lz;
    chx = (fdec(maxU[b * 3 + 0]) - Lx) * sc + 1e-30f;
    chy = (fdec(maxU[b * 3 + 1]) - Ly) * sc + 1e-30f;
    chz = (fdec(maxU[b * 3 + 2]) - Lz) * sc + 1e-30f;
}

// Compare-exchange: insert candidate (c,ci) into slot (k,ki); larger goes on.
#define CE_FULL(k, ki, c, ci)                          \
    {                                                  \
        const bool sw = (c) < (k);                     \
        const float vmn = fminf(k, c);                 \
        const float vmx = fmaxf(k, c);                 \
        const u32 nki = sw ? (ci) : (ki);              \
        const u32 nci = sw ? (ki) : (ci);              \
        (k) = vmn; (c) = vmx; (ki) = nki; (ci) = nci;  \
    }
#define CE_LAST(k, ki, c, ci)                          \
    {                                                  \
        const bool sw = (c) < (k);                     \
        (ki) = sw ? (ci) : (ki);                       \
        (k) = fminf(k, c);                             \
    }

// exact ladder on d2' = |p|^2 - 2 q.p (qq deferred; order preserved)
#define LAD(P, CI)                                     \
    {                                                  \
        float t_ = qx * (P).x;                         \
        t_ = fmaf(qy, (P).y, t_);                      \
        t_ = fmaf(qz, (P).z, t_);                      \
        float c_ = fmaf(-2.0f, t_, (P).w);             \
        u32 ci_ = (u32)(CI);                           \
        CE_FULL(e0, i0, c_, ci_)                       \
        CE_FULL(e1, i1, c_, ci_)                       \
        CE_FULL(e2, i2, c_, ci_)                       \
        CE_FULL(e3, i3, c_, ci_)                       \
        CE_LAST(e4, i4, c_, ci_)                       \
    }

// ---------------- legacy brute path (ws-too-small fallback) ----------------

__global__ __launch_bounds__(256)
void prep_kernel(const float* __restrict__ sxyz, const int* __restrict__ rf,
                 float4* __restrict__ pts, int M, int total) {
    const int t = blockIdx.x * 256 + threadIdx.x;
    if (t >= total) return;
    const float inv = get_inv_sigma(rf);
    const int b = t / M, m = t - b * M;
    const float* sb = sxyz + (size_t)b * 3 * M;
    const float x = sb[m] * inv;
    const float y = sb[M + m] * inv;
    const float z = sb[2 * M + m] * inv;
    pts[t] = make_float4(x, y, z, fmaf(x, x, fmaf(y, y, z * z)));
}

template <bool USE_PTS>
__global__ __launch_bounds__(BLOCK, 8)
void knn_kernel(const float* __restrict__ xyz,
                const float* __restrict__ sxyz,
                const float* __restrict__ sflow,
                const int* __restrict__ rf,
                const float4* __restrict__ pts,
                float* __restrict__ out,
                int N, int M) {
    __shared__ float sval_d[SLICES * KNN * 64];
    __shared__ u32   sval_i[SLICES * KNN * 64];

    const int tid  = threadIdx.x;
    const int lane = tid & 63;
    const int wid  = tid >> 6;
    const int swid = __builtin_amdgcn_readfirstlane(wid);
    const int gpb  = N / 64;
    const int b    = blockIdx.x / gpb;
    const int grp  = blockIdx.x - b * gpb;
    const int n    = grp * 64 + lane;

    const float inv = get_inv_sigma(rf);
    const float* qb = xyz + (size_t)b * 3 * N;
    const float qx = qb[n] * inv;
    const float qy = qb[N + n] * inv;
    const float qz = qb[2 * N + n] * inv;
    const float qq = fmaf(qx, qx, fmaf(qy, qy, qz * qz));

    const int CH = M / SLICES;
    const int j0 = swid * CH;

    float e0 = 1e30f, e1 = 1e30f, e2 = 1e30f, e3 = 1e30f, e4 = 1e30f;
    u32   i0 = 0, i1 = 0, i2 = 0, i3 = 0, i4 = 0;

    if constexpr (USE_PTS) {
        const float4* __restrict__ P = pts + (size_t)b * M + j0;
#pragma unroll 4
        for (int j = 0; j < CH; ++j) {
            const float4 p = P[j];
            LAD(p, j0 + j)
        }
    } else {
        const float* __restrict__ sb = sxyz + (size_t)b * 3 * M;
#pragma unroll 4
        for (int j = 0; j < CH; ++j) {
            const float px = sb[j0 + j] * inv;
            const float py = sb[M + j0 + j] * inv;
            const float pz = sb[2 * M + j0 + j] * inv;
            const float pw = fmaf(px, px, fmaf(py, py, pz * pz));
            const float4 p = make_float4(px, py, pz, pw);
            LAD(p, j0 + j)
        }
    }

    sval_d[(wid * KNN + 0) * 64 + lane] = e0;  sval_i[(wid * KNN + 0) * 64 + lane] = i0;
    sval_d[(wid * KNN + 1) * 64 + lane] = e1;  sval_i[(wid * KNN + 1) * 64 + lane] = i1;
    sval_d[(wid * KNN + 2) * 64 + lane] = e2;  sval_i[(wid * KNN + 2) * 64 + lane] = i2;
    sval_d[(wid * KNN + 3) * 64 + lane] = e3;  sval_i[(wid * KNN + 3) * 64 + lane] = i3;
    sval_d[(wid * KNN + 4) * 64 + lane] = e4;  sval_i[(wid * KNN + 4) * 64 + lane] = i4;
    __syncthreads();

    if (wid == 0) {
        float m0 = 1e30f, m1 = 1e30f, m2 = 1e30f, m3 = 1e30f, m4 = 1e30f;
        u32   g0 = 0, g1 = 0, g2 = 0, g3 = 0, g4 = 0;
#pragma unroll
        for (int w = 0; w < SLICES; ++w) {
#pragma unroll
            for (int k = 0; k < KNN; ++k) {
                float c = sval_d[(w * KNN + k) * 64 + lane];
                u32  ci = sval_i[(w * KNN + k) * 64 + lane];
                CE_FULL(m0, g0, c, ci)
                CE_FULL(m1, g1, c, ci)
                CE_FULL(m2, g2, c, ci)
                CE_FULL(m3, g3, c, ci)
                CE_LAST(m4, g4, c, ci)
            }
        }

        const float d0 = sqrtf(fmaxf(m0 + qq, 1e-12f));
        const float d1 = sqrtf(fmaxf(m1 + qq, 1e-12f));
        const float d2 = sqrtf(fmaxf(m2 + qq, 1e-12f));
        const float d3 = sqrtf(fmaxf(m3 + qq, 1e-12f));
        const float d4 = sqrtf(fmaxf(m4 + qq, 1e-12f));
        const float w0 = 1.0f;
        const float w1 = expf(d0 - d1);
        const float w2 = expf(d0 - d2);
        const float w3 = expf(d0 - d3);
        const float w4 = expf(d0 - d4);
        const float inv_wsum = 1.0f / (w0 + w1 + w2 + w3 + w4);

        const float* fb = sflow + (size_t)b * 3 * M;
        float ax = 0.f, ay = 0.f, az = 0.f;
        ax = fmaf(w0, fb[g0], ax); ay = fmaf(w0, fb[M + g0], ay); az = fmaf(w0, fb[2 * M + g0], az);
        ax = fmaf(w1, fb[g1], ax); ay = fmaf(w1, fb[M + g1], ay); az = fmaf(w1, fb[2 * M + g1], az);
        ax = fmaf(w2, fb[g2], ax); ay = fmaf(w2, fb[M + g2], ay); az = fmaf(w2, fb[2 * M + g2], az);
        ax = fmaf(w3, fb[g3], ax); ay = fmaf(w3, fb[M + g3], ay); az = fmaf(w3, fb[2 * M + g3], az);
        ax = fmaf(w4, fb[g4], ax); ay = fmaf(w4, fb[M + g4], ay); az = fmaf(w4, fb[2 * M + g4], az);

        float* ob = out + (size_t)b * 3 * N;
        ob[n]         = ax * inv_wsum;
        ob[N + n]     = ay * inv_wsum;
        ob[2 * N + n] = az * inv_wsum;
    }
}

// ---------------- parallel prep: bbox / hist / scan / scatter ----------------

__global__ __launch_bounds__(256)
void bbox_atomic_kernel(const float* __restrict__ sxyz, const int* __restrict__ rf,
                        u32* __restrict__ minU, u32* __restrict__ maxU, int M) {
    const int per = M / 256;                       // blocks per batch
    const int b = blockIdx.x / per;
    const int m = (blockIdx.x - b * per) * 256 + threadIdx.x;
    const float inv = get_inv_sigma(rf);
    const float* sb = sxyz + (size_t)b * 3 * M;
    const float x = sb[m] * inv, y = sb[M + m] * inv, z = sb[2 * M + m] * inv;
    float lx = x, ly = y, lz = z, hx = x, hy = y, hz = z;
#pragma unroll
    for (int mm = 1; mm < 64; mm <<= 1) {
        lx = fminf(lx, __shfl_xor(lx, mm, 64));
        ly = fminf(ly, __shfl_xor(ly, mm, 64));
        lz = fminf(lz, __shfl_xor(lz, mm, 64));
        hx = fmaxf(hx, __shfl_xor(hx, mm, 64));
        hy = fmaxf(hy, __shfl_xor(hy, mm, 64));
        hz = fmaxf(hz, __shfl_xor(hz, mm, 64));
    }
    if ((threadIdx.x & 63) == 0) {
        atomicMin(&minU[b * 3 + 0], fenc(lx));
        atomicMin(&minU[b * 3 + 1], fenc(ly));
        atomicMin(&minU[b * 3 + 2], fenc(lz));
        atomicMax(&maxU[b * 3 + 0], fenc(hx));
        atomicMax(&maxU[b * 3 + 1], fenc(hy));
        atomicMax(&maxU[b * 3 + 2], fenc(hz));
    }
}

__global__ __launch_bounds__(256)
void hist_kernel2(const float* __restrict__ xyz, const float* __restrict__ sxyz,
                  const int* __restrict__ rf, const u32* __restrict__ minU,
                  const u32* __restrict__ maxU, int* __restrict__ histAll,
                  int N, int M, int B) {
    const int t = blockIdx.x * 256 + threadIdx.x;
    const int TC = B * M;
    const float inv = get_inv_sigma(rf);
    float x, y, z; int b, slice;
    if (t < TC) {
        b = t / M; const int i = t - b * M;
        const float* sb = sxyz + (size_t)b * 3 * M;
        x = sb[i] * inv; y = sb[M + i] * inv; z = sb[2 * M + i] * inv;
        slice = b;
    } else if (t < TC + B * N) {
        const int t2 = t - TC;
        b = t2 / N; const int i = t2 - b * N;
        const float* qb = xyz + (size_t)b * 3 * N;
        x = qb[i] * inv; y = qb[N + i] * inv; z = qb[2 * N + i] * inv;
        slice = B + b;
    } else return;
    float lox, loy, loz, chx, chy, chz;
    bb_load(minU, maxU, b, lox, loy, loz, chx, chy, chz);
    const int cell = (sp3(cid1(x, lox, 1.0f / chx)) << 2) |
                     (sp3(cid1(y, loy, 1.0f / chy)) << 1) |
                      sp3(cid1(z, loz, 1.0f / chz));
    atomicAdd(&histAll[(size_t)slice * NCELL + cell], 1);
}

__global__ __launch_bounds__(NCELL)
void scan_kernel2(const int* __restrict__ histAll, int2* __restrict__ off2C,
                  int* __restrict__ curAll, int B) {
    __shared__ int sc[NCELL];
    const int s = blockIdx.x;          // 0..2B-1
    const int t = threadIdx.x;         // 0..NCELL-1
    const int h = histAll[(size_t)s * NCELL + t];
    sc[t] = h;
    __syncthreads();
    for (int d = 1; d < NCELL; d <<= 1) {
        const int v = (t >= d) ? sc[t - d] : 0;
        __syncthreads();
        sc[t] += v;
        __syncthreads();
    }
    const int excl = sc[t] - h;
    curAll[(size_t)s * NCELL + t] = excl;
    if (s < B) off2C[(size_t)s * NCELL + t] = make_int2(excl, excl + h);
}

__global__ __launch_bounds__(256)
void scatter_kernel2(const float* __restrict__ xyz, const float* __restrict__ sxyz,
                     const int* __restrict__ rf, const u32* __restrict__ minU,
                     const u32* __restrict__ maxU, int* __restrict__ curAll,
                     float4* __restrict__ ptsS, float4* __restrict__ qS,
                     int* __restrict__ idxS, int N, int M, int B) {
    const int t = blockIdx.x * 256 + threadIdx.x;
    const int TC = B * M;
    const float inv = get_inv_sigma(rf);
    float x, y, z; int b, i, slice;
    bool isQ;
    if (t < TC) {
        b = t / M; i = t - b * M;
        const float* sb = sxyz + (size_t)b * 3 * M;
        x = sb[i] * inv; y = sb[M + i] * inv; z = sb[2 * M + i] * inv;
        slice = b; isQ = false;
    } else if (t < TC + B * N) {
        const int t2 = t - TC;
        b = t2 / N; i = t2 - b * N;
        const float* qb = xyz + (size_t)b * 3 * N;
        x = qb[i] * inv; y = qb[N + i] * inv; z = qb[2 * N + i] * inv;
        slice = B + b; isQ = true;
    } else return;
    float lox, loy, loz, chx, chy, chz;
    bb_load(minU, maxU, b, lox, loy, loz, chx, chy, chz);
    const int cell = (sp3(cid1(x, lox, 1.0f / chx)) << 2) |
                     (sp3(cid1(y, loy, 1.0f / chy)) << 1) |
                      sp3(cid1(z, loz, 1.0f / chz));
    const int slot = atomicAdd(&curAll[(size_t)slice * NCELL + cell], 1);
    if (isQ) {
        qS[(size_t)b * N + slot] = make_float4(x, y, z, __int_as_float(i));
    } else {
        ptsS[(size_t)b * M + slot] = make_float4(x, y, z, fmaf(x, x, fmaf(y, y, z * z)));
        idxS[(size_t)b * M + slot] = i;
    }
}

// ---------------- main grid kNN: phase-1 bootstrap + per-lane pruned rings ----------------

// per-lane cell test + scan. needs: dxy2 (per-lane), mxy, chz/loz, qz, e4, qq.
#define CELLP(CZ)                                                               \
    {                                                                           \
        const float glz_ = fmaf((float)(CZ), chz, loz);                         \
        const float cqz_ = fminf(fmaxf(qz, glz_), glz_ + chz);                  \
        const float dzl_ = qz - cqz_;                                           \
        const float d3_ = fmaf(dzl_, dzl_, dxy2);                               \
        const float cmp_ = fmaf(e4 + qq, 1.00001f, EPSM);                       \
        if (!__all(d3_ > cmp_)) {                                               \
            const int cell_ = mxy | sp3(CZ);                                    \
            const int2 oo_ = off2b[cell_];                                      \
            const int base_ = __builtin_amdgcn_readfirstlane(oo_.x);            \
            const int end_ = __builtin_amdgcn_readfirstlane(oo_.y);             \
            int j_ = base_;                                                     \
            for (; j_ + 4 <= end_; j_ += 4) {                                   \
                const float4 p0_ = Pb[j_];                                      \
                const float4 p1_ = Pb[j_ + 1];                                  \
                const float4 p2_ = Pb[j_ + 2];                                  \
                const float4 p3_ = Pb[j_ + 3];                                  \
                LAD(p0_, j_) LAD(p1_, j_ + 1)                                   \
                LAD(p2_, j_ + 2) LAD(p3_, j_ + 3)                               \
            }                                                                   \
            for (; j_ < end_; ++j_) {                                           \
                const float4 pp_ = Pb[j_];                                      \
                LAD(pp_, j_)                                                    \
            }                                                                   \
        }                                                                       \
    }

__global__ __launch_bounds__(BLOCK, 8)
void knn_grid8_kernel(const float4* __restrict__ qS, const float4* __restrict__ ptsS,
                      const int* __restrict__ idxS, const int2* __restrict__ off2C,
                      const u32* __restrict__ minU, const u32* __restrict__ maxU,
                      const float* __restrict__ sflow,
                      float* __restrict__ out, int N, int M) {
    __shared__ float sval_d[SLICES * KNN * 64];   // 10 KB
    __shared__ u32   sval_i[SLICES * KNN * 64];   // 10 KB
    __shared__ float se4[SLICES * 64];            //  2 KB

    const int tid  = threadIdx.x;
    const int lane = tid & 63;
    const int wid  = tid >> 6;
    const int swid = __builtin_amdgcn_readfirstlane(wid);
    const int gpb  = N >> 6;
    const int b    = blockIdx.x / gpb;
    const int grp  = blockIdx.x - b * gpb;

    const float4 q4 = qS[(size_t)b * N + grp * 64 + lane];
    const float qx = q4.x, qy = q4.y, qz = q4.z;
    const int n = __float_as_int(q4.w);
    const float qq = fmaf(qx, qx, fmaf(qy, qy, qz * qz));

    // wave AABB (span + ring geometry only; pruning is per-lane now)
    float wlx = qx, wly = qy, wlz = qz, whx = qx, why = qy, whz = qz;
#pragma unroll
    for (int m = 1; m < 64; m <<= 1) {
        wlx = fminf(wlx, __shfl_xor(wlx, m, 64));
        whx = fmaxf(whx, __shfl_xor(whx, m, 64));
        wly = fminf(wly, __shfl_xor(wly, m, 64));
        why = fmaxf(why, __shfl_xor(why, m, 64));
        wlz = fminf(wlz, __shfl_xor(wlz, m, 64));
        whz = fmaxf(whz, __shfl_xor(whz, m, 64));
    }
    wlx = rfl_f(wlx) - EPSM; whx = rfl_f(whx) + EPSM;
    wly = rfl_f(wly) - EPSM; why = rfl_f(why) + EPSM;
    wlz = rfl_f(wlz) - EPSM; whz = rfl_f(whz) + EPSM;

    float lox, loy, loz, chx, chy, chz;
    bb_load(minU, maxU, b, lox, loy, loz, chx, chy, chz);
    const float hmin = fminf(chx, fminf(chy, chz));

    const int clx = cid1(wlx, lox, 1.0f / chx), cxh = cid1(whx, lox, 1.0f / chx);
    const int cly = cid1(wly, loy, 1.0f / chy), cyh = cid1(why, loy, 1.0f / chy);
    const int clz = cid1(wlz, loz, 1.0f / chz), czh = cid1(whz, loz, 1.0f / chz);

    float e0 = 1e30f, e1 = 1e30f, e2 = 1e30f, e3 = 1e30f, e4 = 1e30f;
    u32   i0 = 0, i1 = 0, i2 = 0, i3 = 0, i4 = 0;

    const float4* __restrict__ Pb = ptsS + (size_t)b * M;
    const int2* __restrict__ off2b = off2C + (size_t)b * NCELL;

    const int span = (cxh - clx + 1) * (cyh - cly + 1) * (czh - clz + 1);
    if (span > SPAN_TH) {
        // inline sliced brute over sorted candidates (Morton seams, rare).
        // block-uniform branch (all waves share the same 64 queries).
        const int CH = M / SLICES;
        const int j0 = swid * CH;
        const float4* __restrict__ P = Pb + j0;
#pragma unroll 4
        for (int j = 0; j < CH; ++j) {
            const float4 p = P[j];
            LAD(p, j0 + j)
        }
    } else {
        int ctr = 0;
        // ---- phase 1: cooperative span-box scan (cell ownership) ----
        for (int cx = clx; cx <= cxh; ++cx) {
            const float glx = fmaf((float)cx, chx, lox);
            const float cqx = fminf(fmaxf(qx, glx), glx + chx);
            const float dxl = qx - cqx;
            const float dxx = dxl * dxl;
            const int mx = sp3(cx) << 2;
            for (int cy = cly; cy <= cyh; ++cy) {
                const float gly = fmaf((float)cy, chy, loy);
                const float cqy = fminf(fmaxf(qy, gly), gly + chy);
                const float dyl = qy - cqy;
                const float dxy2 = fmaf(dyl, dyl, dxx);
                const int mxy = mx | (sp3(cy) << 1);
                for (int cz = clz; cz <= czh; ++cz) {
                    if (((ctr++) & 7) == wid) { CELLP(cz) }
                }
            }
        }
        // ---- cross-wave bound merge (deterministic, one barrier):
        // per-lane: min over waves of e4, then +qq, then max over lanes.
        // merged-5th(l) <= min_w e4_w(l), so this bounds every lane's
        // global 5th-best squared distance.
        se4[wid * 64 + lane] = e4;
        __syncthreads();
        float bnd = se4[lane];
#pragma unroll
        for (int w = 1; w < SLICES; ++w) bnd = fminf(bnd, se4[w * 64 + lane]);
        bnd += qq;
#pragma unroll
        for (int mm = 1; mm < 64; mm <<= 1) bnd = fmaxf(bnd, __shfl_xor(bnd, mm, 64));
        float TwR = rfl_f(bnd);

        // ---- phase 2: expanding rings, per-lane pruned; deterministic
        // termination from min(phase-1 bound, own-wave max(e4+qq)). ----
        for (int r = 1; r <= GRID; ++r) {
            float own = e4 + qq;                 // per-lane 5th-best (own wave)
#pragma unroll
            for (int mm = 1; mm < 64; mm <<= 1) own = fmaxf(own, __shfl_xor(own, mm, 64));
            TwR = fminf(TwR, rfl_f(own));
            if (r >= 2) {
                const float bd = (float)(r - 1) * hmin - EPSM;
                if (bd > 0.0f && bd * bd > fmaf(TwR, 1.00001f, EPSM)) break;
            }
            const int x0 = clx - r < 0 ? 0 : clx - r;
            const int x1 = cxh + r > GRID - 1 ? GRID - 1 : cxh + r;
            const int y0 = cly - r < 0 ? 0 : cly - r;
            const int y1 = cyh + r > GRID - 1 ? GRID - 1 : cyh + r;
            const int z0 = clz - r < 0 ? 0 : clz - r;
            const int z1 = czh + r > GRID - 1 ? GRID - 1 : czh + r;
            for (int cx = x0; cx <= x1; ++cx) {
                const int rx = cx < clx ? clx - cx : (cx > cxh ? cx - cxh : 0);
                const float glx = fmaf((float)cx, chx, lox);
                const float cqx = fminf(fmaxf(qx, glx), glx + chx);
                const float dxl = qx - cqx;
                const float dxx = dxl * dxl;
                const int mx = sp3(cx) << 2;
                for (int cy = y0; cy <= y1; ++cy) {
                    const int ry = cy < cly ? cly - cy : (cy > cyh ? cy - cyh : 0);
                    if (((ctr++) & 7) == wid) {
                        const float gly = fmaf((float)cy, chy, loy);
                        const float cqy = fminf(fmaxf(qy, gly), gly + chy);
                        const float dyl = qy - cqy;
                        const float dxy2 = fmaf(dyl, dyl, dxx);
                        const float cmpc = fmaf(e4 + qq, 1.00001f, EPSM);
                        if (!__all(dxy2 > cmpc)) {
                            const int mxy = mx | (sp3(cy) << 1);
                            if ((rx > ry ? rx : ry) == r) {
                                for (int cz = z0; cz <= z1; ++cz) { CELLP(cz) }
                            } else {
                                if (clz - r >= 0) { CELLP(clz - r) }
                                if (czh + r <= GRID - 1) { CELLP(czh + r) }
                            }
                        }
                    }
                }
            }
        }
    }

    sval_d[(wid * KNN + 0) * 64 + lane] = e0;  sval_i[(wid * KNN + 0) * 64 + lane] = i0;
    sval_d[(wid * KNN + 1) * 64 + lane] = e1;  sval_i[(wid * KNN + 1) * 64 + lane] = i1;
    sval_d[(wid * KNN + 2) * 64 + lane] = e2;  sval_i[(wid * KNN + 2) * 64 + lane] = i2;
    sval_d[(wid * KNN + 3) * 64 + lane] = e3;  sval_i[(wid * KNN + 3) * 64 + lane] = i3;
    sval_d[(wid * KNN + 4) * 64 + lane] = e4;  sval_i[(wid * KNN + 4) * 64 + lane] = i4;
    __syncthreads();

    if (wid == 0) {
        float m0 = 1e30f, m1 = 1e30f, m2 = 1e30f, m3 = 1e30f, m4 = 1e30f;
        u32 g0 = 0, g1 = 0, g2 = 0, g3 = 0, g4 = 0;
#pragma unroll
        for (int w = 0; w < SLICES; ++w) {
#pragma unroll
            for (int k = 0; k < KNN; ++k) {
                float c = sval_d[(w * KNN + k) * 64 + lane];
                u32 ci = sval_i[(w * KNN + k) * 64 + lane];
                CE_FULL(m0, g0, c, ci)
                CE_FULL(m1, g1, c, ci)
                CE_FULL(m2, g2, c, ci)
                CE_FULL(m3, g3, c, ci)
                CE_LAST(m4, g4, c, ci)
            }
        }

        const float d0 = sqrtf(fmaxf(m0 + qq, 1e-12f));
        const float d1 = sqrtf(fmaxf(m1 + qq, 1e-12f));
        const float d2 = sqrtf(fmaxf(m2 + qq, 1e-12f));
        const float d3 = sqrtf(fmaxf(m3 + qq, 1e-12f));
        const float d4 = sqrtf(fmaxf(m4 + qq, 1e-12f));
        const float w0 = 1.0f;
        const float w1 = expf(d0 - d1);
        const float w2 = expf(d0 - d2);
        const float w3 = expf(d0 - d3);
        const float w4 = expf(d0 - d4);
        const float inv_wsum = 1.0f / (w0 + w1 + w2 + w3 + w4);

        const int* __restrict__ idxb = idxS + (size_t)b * M;
        const int o0 = idxb[g0], o1 = idxb[g1], o2 = idxb[g2], o3 = idxb[g3], o4 = idxb[g4];
        const float* fb = sflow + (size_t)b * 3 * M;
        float ax = 0.f, ay = 0.f, az = 0.f;
        ax = fmaf(w0, fb[o0], ax); ay = fmaf(w0, fb[M + o0], ay); az = fmaf(w0, fb[2 * M + o0], az);
        ax = fmaf(w1, fb[o1], ax); ay = fmaf(w1, fb[M + o1], ay); az = fmaf(w1, fb[2 * M + o1], az);
        ax = fmaf(w2, fb[o2], ax); ay = fmaf(w2, fb[M + o2], ay); az = fmaf(w2, fb[2 * M + o2], az);
        ax = fmaf(w3, fb[o3], ax); ay = fmaf(w3, fb[M + o3], ay); az = fmaf(w3, fb[2 * M + o3], az);
        ax = fmaf(w4, fb[o4], ax); ay = fmaf(w4, fb[M + o4], ay); az = fmaf(w4, fb[2 * M + o4], az);

        float* ob = out + (size_t)b * 3 * N;
        ob[n]         = ax * inv_wsum;
        ob[N + n]     = ay * inv_wsum;
        ob[2 * N + n] = az * inv_wsum;
    }
}

extern "C" void kernel_launch(void* const* d_in, const int* in_sizes, int n_in,
                              void* d_out, int out_size, void* d_ws, size_t ws_size,
                              hipStream_t stream) {
    const float* xyz   = (const float*)d_in[0];
    const float* sxyz  = (const float*)d_in[1];
    const float* sflow = (const float*)d_in[2];
    const int*   rf    = (const int*)d_in[3];

    const int B = 4;
    const int N = in_sizes[0] / (3 * B);    // 16384
    const int M = in_sizes[1] / (3 * B);    // 4096
    float* out = (float*)d_out;

    // workspace layout (maxU and histAll contiguous for one zero-memset)
    size_t o = 0;
    float4* ptsS  = (float4*)((char*)d_ws + o); o += (size_t)B * M * sizeof(float4);
    float4* qS    = (float4*)((char*)d_ws + o); o += (size_t)B * N * sizeof(float4);
    int*   idxS   = (int*)((char*)d_ws + o);    o += (size_t)B * M * 4;
    u32*   minU   = (u32*)((char*)d_ws + o);    o += (size_t)B * 3 * 4;
    u32*   maxU   = (u32*)((char*)d_ws + o);    o += (size_t)B * 3 * 4;
    int*   histAll= (int*)((char*)d_ws + o);    o += (size_t)2 * B * NCELL * 4;
    int*   curAll = (int*)((char*)d_ws + o);    o += (size_t)2 * B * NCELL * 4;
    int2*  off2C  = (int2*)((char*)d_ws + o);   o += (size_t)B * NCELL * 8;
    const size_t need = o;

    if (ws_size >= need && (N % 64) == 0 && (M % 256) == 0) {
        const int total = B * (M + N);
        hipMemsetAsync(minU, 0xFF, (size_t)B * 3 * 4, stream);
        hipMemsetAsync(maxU, 0x00, (size_t)B * 3 * 4 + (size_t)2 * B * NCELL * 4, stream);
        bbox_atomic_kernel<<<dim3(B * (M / 256)), dim3(256), 0, stream>>>(
            sxyz, rf, minU, maxU, M);
        hist_kernel2<<<dim3((total + 255) / 256), dim3(256), 0, stream>>>(
            xyz, sxyz, rf, minU, maxU, histAll, N, M, B);
        scan_kernel2<<<dim3(2 * B), dim3(NCELL), 0, stream>>>(
            histAll, off2C, curAll, B);
        scatter_kernel2<<<dim3((total + 255) / 256), dim3(256), 0, stream>>>(
            xyz, sxyz, rf, minU, maxU, curAll, ptsS, qS, idxS, N, M, B);
        knn_grid8_kernel<<<dim3(B * (N / 64)), dim3(BLOCK), 0, stream>>>(
            qS, ptsS, idxS, off2C, minU, maxU, sflow, out, N, M);
    } else {
        const dim3 grid(B * (N / 64));
        const dim3 block(BLOCK);
        const size_t needOld = (size_t)B * M * sizeof(float4);
        if (ws_size >= needOld) {
            float4* pts = (float4*)d_ws;
            prep_kernel<<<dim3((B * M + 255) / 256), dim3(256), 0, stream>>>(
                sxyz, rf, pts, M, B * M);
            knn_kernel<true><<<grid, block, 0, stream>>>(xyz, sxyz, sflow, rf, pts, out, N, M);
        } else {
            knn_kernel<false><<<grid, block, 0, stream>>>(xyz, sxyz, sflow, rf, nullptr, out, N, M);
        }
    }
}